// Round 1
// baseline (831.112 us; speedup 1.0000x reference)
//
#include <hip/hip_runtime.h>
#include <stdint.h>

// ---------- types & helpers ----------
typedef short s16x8 __attribute__((ext_vector_type(8)));
typedef float f32x4 __attribute__((ext_vector_type(4)));

#define MFMA_BF16(a,b,c) __builtin_amdgcn_mfma_f32_16x16x32_bf16((a),(b),(c),0,0,0)

static __device__ __forceinline__ float bf2f(unsigned short b){
  return __uint_as_float(((unsigned)b)<<16);
}
static __device__ __forceinline__ unsigned short f2bf(float f){
  unsigned u = __float_as_uint(f);
  unsigned r = u + 0x7FFFu + ((u>>16)&1u);
  return (unsigned short)(r>>16);
}
static __device__ __forceinline__ void store_val(float* p, float v){ *p = v; }
static __device__ __forceinline__ void store_val(unsigned short* p, float v){ *p = f2bf(v); }

// order-preserving float->u32 (descending float == descending u32), +-0 canonicalized
static __device__ __forceinline__ unsigned ordf(float f){
  if (f == 0.0f) return 0x80000000u;
  unsigned u = __float_as_uint(f);
  return (u & 0x80000000u) ? ~u : (u | 0x80000000u);
}

typedef __attribute__((address_space(1))) const void g_void;
typedef __attribute__((address_space(3))) void l_void;
static __device__ __forceinline__ void gload_lds16(const void* g, void* lds){
  __builtin_amdgcn_global_load_lds((g_void*)g, (l_void*)lds, 16, 0, 0);
}

// ---------- elementwise convert f32 -> bf16 ----------
__global__ __launch_bounds__(256) void k_f32_to_bf16(const float* __restrict__ in,
                                                     unsigned short* __restrict__ out, int n){
  int i = blockIdx.x*256 + threadIdx.x;
  int stride = gridDim.x*256;
  for(; i<n; i+=stride) out[i] = f2bf(in[i]);
}

// ---------- transpose: in[R][C] f32 -> out[C][R] (OT = float or bf16-bits) ----------
template<typename OT>
__global__ __launch_bounds__(256) void k_transpose(const float* __restrict__ in, OT* __restrict__ out,
                                                   int R, int C, long inStride, long outStride){
  __shared__ float tile[32][33];
  const float* inb = in + (long)blockIdx.z*inStride;
  OT* outb = out + (long)blockIdx.z*outStride;
  int tx = threadIdx.x, ty = threadIdx.y;        // block (32,8)
  int c0 = blockIdx.x*32, r0 = blockIdx.y*32;
#pragma unroll
  for(int j=0;j<4;j++) tile[ty+j*8][tx] = inb[(long)(r0+ty+j*8)*C + c0 + tx];
  __syncthreads();
#pragma unroll
  for(int j=0;j<4;j++) store_val(&outb[(long)(c0+ty+j*8)*R + r0 + tx], tile[tx][ty+j*8]);
}

// ---------- generic f32 GEMM: C[M][N] = A[M][K]*B[K][N]  (M%64==0, K%16==0, N bounds-checked) ----------
__global__ __launch_bounds__(256) void k_gemm_f32(const float* __restrict__ A, const float* __restrict__ B,
                                                  float* __restrict__ C, int M, int N, int K){
  __shared__ float As[64][17];
  __shared__ float Bs[16][68];
  int tid = threadIdx.x;
  int tx = tid & 15, ty = tid >> 4;
  int m0 = blockIdx.x*64, n0 = blockIdx.y*64;
  float acc[4][4] = {};
  for(int k0=0; k0<K; k0+=16){
#pragma unroll
    for(int i=0;i<4;i++){
      int e = tid + i*256; int rr = e>>4, cc = e&15;
      As[rr][cc] = A[(long)(m0+rr)*K + k0 + cc];
    }
#pragma unroll
    for(int i=0;i<4;i++){
      int e = tid + i*256; int rr = e>>6, cc = e&63;
      int n = n0 + cc;
      Bs[rr][cc] = (n<N) ? B[(long)(k0+rr)*N + n] : 0.f;
    }
    __syncthreads();
#pragma unroll
    for(int kk=0;kk<16;kk++){
      float av[4], bv[4];
#pragma unroll
      for(int i=0;i<4;i++) av[i] = As[ty*4+i][kk];
#pragma unroll
      for(int j=0;j<4;j++) bv[j] = Bs[kk][tx*4+j];
#pragma unroll
      for(int i=0;i<4;i++)
#pragma unroll
        for(int j=0;j<4;j++) acc[i][j] = fmaf(av[i], bv[j], acc[i][j]);
    }
    __syncthreads();
  }
#pragma unroll
  for(int i=0;i<4;i++){
    int m = m0 + ty*4 + i;
#pragma unroll
    for(int j=0;j<4;j++){
      int n = n0 + tx*4 + j;
      if(n<N) C[(long)m*N + n] = acc[i][j];
    }
  }
}

// ---------- bf16 MFMA GEMM: C[M][N] = A[M][K] * BT[N][K]^T ; dims % {128,128,32} ----------
template<typename OT>
__global__ __launch_bounds__(256) void k_gemm_bf16(const unsigned short* __restrict__ A,
                                                   const unsigned short* __restrict__ BT,
                                                   OT* __restrict__ C, int M, int N, int K){
  __shared__ __align__(16) unsigned short As[128*32];
  __shared__ __align__(16) unsigned short Bs[128*32];
  int tid = threadIdx.x;
  int w = tid>>6, l = tid&63;
  int fr = l&15, fg = l>>4;
  int wm = (w>>1)*64, wn = (w&1)*64;
  long m0 = (long)blockIdx.x*128, n0 = (long)blockIdx.y*128;
  f32x4 acc[4][4];
#pragma unroll
  for(int i=0;i<4;i++)
#pragma unroll
    for(int j=0;j<4;j++){ f32x4 z = {0.f,0.f,0.f,0.f}; acc[i][j]=z; }

  for(int k0=0;k0<K;k0+=32){
    __syncthreads();
#pragma unroll
    for(int i=0;i<2;i++){
      int eo = (w*64 + l)*8 + i*2048;       // element offset in [128][32] tile
      int rr = eo>>5, cc = eo&31;
      gload_lds16(A + (m0+rr)*K + k0 + cc, (char*)As + w*1024 + i*4096);
    }
#pragma unroll
    for(int i=0;i<2;i++){
      int eo = (w*64 + l)*8 + i*2048;
      int rr = eo>>5, cc = eo&31;
      gload_lds16(BT + (n0+rr)*K + k0 + cc, (char*)Bs + w*1024 + i*4096);
    }
    asm volatile("s_waitcnt vmcnt(0)" ::: "memory");
    __syncthreads();
    s16x8 af[4], bfr[4];
#pragma unroll
    for(int mf=0;mf<4;mf++) af[mf]  = *(const s16x8*)&As[(wm + mf*16 + fr)*32 + fg*8];
#pragma unroll
    for(int nf=0;nf<4;nf++) bfr[nf] = *(const s16x8*)&Bs[(wn + nf*16 + fr)*32 + fg*8];
#pragma unroll
    for(int mf=0;mf<4;mf++)
#pragma unroll
      for(int nf=0;nf<4;nf++)
        acc[mf][nf] = MFMA_BF16(af[mf], bfr[nf], acc[mf][nf]);
  }
#pragma unroll
  for(int mf=0;mf<4;mf++)
#pragma unroll
    for(int nf=0;nf<4;nf++)
#pragma unroll
      for(int r=0;r<4;r++){
        long m = m0 + wm + mf*16 + fg*4 + r;
        long n = n0 + wn + nf*16 + fr;
        store_val(&C[m*N + n], acc[mf][nf][r]);
      }
}

// ---------- RoPE tables ----------
__global__ __launch_bounds__(256) void k_rope_tab(float* __restrict__ cosT, float* __restrict__ sinT){
  int i = blockIdx.x*256 + threadIdx.x;   // 2048*32
  int t = i>>5, p = i&31;
  float theta = exp2f(-(float)p * (13.287712379549449f/32.0f)); // 10000^(-p/32)
  float ang = (float)t * theta;
  cosT[i] = cosf(ang);
  sinT[i] = sinf(ang);
}

// ---------- RoPE + head-permute: qkv[B*S][3072](bf16) -> Qr,Kr [B,H,S,64] (Q prescaled 0.125), VT [B,H,64,S] ----------
__global__ __launch_bounds__(256) void k_rope_permute(const unsigned short* __restrict__ qkv,
                                                      const float* __restrict__ cosT, const float* __restrict__ sinT,
                                                      unsigned short* __restrict__ Qr, unsigned short* __restrict__ Kr,
                                                      unsigned short* __restrict__ VT){
  int st = blockIdx.x, h = blockIdx.y, b = blockIdx.z;
  int tid = threadIdx.x;
  __shared__ float vt[64][65];
  long rowbase = (long)b*2048 + st*64;
#pragma unroll
  for(int part=0; part<2; part++){
    const int colbase = part*1024 + h*64;
    unsigned short* outp = part ? Kr : Qr;
    float prescale = part ? 1.0f : 0.125f;
#pragma unroll
    for(int i=0;i<8;i++){
      int e = tid + i*256;            // 64 rows x 32 pairs
      int row = e>>5, p = e&31;
      long s = (long)st*64 + row;
      const unsigned short* src = qkv + (rowbase+row)*3072 + colbase + 2*p;
      float x0 = bf2f(src[0]), x1 = bf2f(src[1]);
      float c = cosT[s*32+p], sn = sinT[s*32+p];
      float y0 = (x0*c - x1*sn)*prescale;
      float y1 = (x1*c + x0*sn)*prescale;
      unsigned short* dst = outp + ((long)(b*16+h)*2048 + s)*64 + 2*p;
      dst[0] = f2bf(y0); dst[1] = f2bf(y1);
    }
  }
  // V: [64 s][64 d] -> VT[d][s]
#pragma unroll
  for(int i=0;i<16;i++){
    int e = tid + i*256;
    int row = e>>6, col = e&63;
    vt[col][row] = bf2f(qkv[(rowbase+row)*3072 + 2048 + h*64 + col]);
  }
  __syncthreads();
#pragma unroll
  for(int i=0;i<16;i++){
    int e = tid + i*256;
    int d = e>>6, scol = e&63;
    VT[((long)(b*16+h)*64 + d)*2048 + (long)st*64 + scol] = f2bf(vt[d][scol]);
  }
}

// ---------- per-row index scores + exact top-k (stable ties) -> bitmask ----------
__global__ __launch_bounds__(256) void k_topk(const float* __restrict__ iq, const float* __restrict__ ikT,
                                              const float* __restrict__ iw, const int* __restrict__ pk,
                                              unsigned* __restrict__ bmask){
  int t = blockIdx.x, b = blockIdx.y;
  int tid = threadIdx.x;
  int k = pk[0];
  __shared__ float siq[256];
  __shared__ float siw[4];
  __shared__ unsigned su[2048];
  __shared__ unsigned hist[256];
  __shared__ unsigned scan[256];
  __shared__ unsigned words[64];
  __shared__ unsigned sh_b[2];
  long row = (long)b*2048 + t;
  siq[tid] = iq[row*256 + tid];
  if(tid<4) siw[tid] = iw[row*4 + tid];
  __syncthreads();

  int s0 = tid*8;
  if (s0 <= t){
    float acc[4][8];
#pragma unroll
    for(int h=0;h<4;h++)
#pragma unroll
      for(int j=0;j<8;j++) acc[h][j]=0.f;
    const float* ikb = ikT + (long)b*64*2048;
    for(int d=0;d<64;d++){
      const float* prow = ikb + (long)d*2048 + s0;
      float4 v0 = *(const float4*)prow;
      float4 v1 = *(const float4*)(prow+4);
      float ikv[8] = {v0.x,v0.y,v0.z,v0.w,v1.x,v1.y,v1.z,v1.w};
#pragma unroll
      for(int h=0;h<4;h++){
        float q = siq[h*64+d];
#pragma unroll
        for(int j=0;j<8;j++) acc[h][j] = fmaf(q, ikv[j], acc[h][j]);
      }
    }
#pragma unroll
    for(int j=0;j<8;j++){
      int s = s0+j;
      if(s<=t){
        float I = 0.f;
#pragma unroll
        for(int h=0;h<4;h++) I += siw[h]*fmaxf(acc[h][j],0.f);
        su[s] = ordf(I);
      }
    }
  }
  __syncthreads();

  unsigned thr = 0; int kk = 0;
  bool allsel = (t+1 <= k);
  if (!allsel){
    unsigned prefix=0, msk=0;
    kk = k;
    for(int shift=24; shift>=0; shift-=8){
      hist[tid]=0; __syncthreads();
      if(s0<=t){
        for(int j=0;j<8;j++){
          int s=s0+j; if(s>t) break;
          unsigned u=su[s];
          if((u&msk)==prefix) atomicAdd(&hist[(u>>shift)&255],1u);
        }
      }
      __syncthreads();
      if(tid==0){
        unsigned cum=0;
        for(int v=255; v>=0; v--){
          unsigned c=hist[v];
          if(cum+c >= (unsigned)kk){ sh_b[0]=(unsigned)v; sh_b[1]=(unsigned)kk-cum; break; }
          cum+=c;
        }
      }
      __syncthreads();
      prefix |= sh_b[0]<<shift; msk |= 255u<<shift; kk = (int)sh_b[1];
      __syncthreads();
    }
    thr = prefix;
  }

  unsigned gtb=0, eqb=0;
  if (s0 <= t){
    for(int j=0;j<8;j++){
      int s=s0+j; if(s>t) break;
      if(allsel){ gtb |= 1u<<j; }
      else{
        unsigned u=su[s];
        if(u>thr) gtb |= 1u<<j;
        else if(u==thr) eqb |= 1u<<j;
      }
    }
  }
  int cnt = __popc(eqb);
  scan[tid]=(unsigned)cnt; __syncthreads();
  for(int off=1; off<256; off<<=1){
    unsigned v = (tid>=off) ? scan[tid-off] : 0u;
    __syncthreads();
    scan[tid]+=v;
    __syncthreads();
  }
  int excl = (int)scan[tid]-cnt;
  unsigned bits = gtb;
  if(eqb){
    int seen=0;
    for(int j=0;j<8;j++) if((eqb>>j)&1u){ if(excl+seen < kk) bits |= 1u<<j; seen++; }
  }
  if(tid<64) words[tid]=0;
  __syncthreads();
  if(bits) atomicOr(&words[tid>>2], bits << ((tid&3)*8));
  __syncthreads();
  if(tid<64) bmask[row*64 + tid] = words[tid];
}

// ---------- masked flash attention: Qr,Kr [B,H,S,64] bf16 (Q prescaled), VT [B,H,64,S] -> attn [B,S,H*64] bf16 ----------
__global__ __launch_bounds__(256) void k_attn(const unsigned short* __restrict__ Qr,
                                              const unsigned short* __restrict__ Kr,
                                              const unsigned short* __restrict__ VT,
                                              const unsigned* __restrict__ bmask,
                                              unsigned short* __restrict__ attn){
  int ttile = blockIdx.x, h = blockIdx.y, b = blockIdx.z;
  int tid = threadIdx.x, w = tid>>6, l = tid&63;
  int fr = l&15, fg = l>>4;
  __shared__ __align__(16) unsigned short P[4][16][72];
  const unsigned short* Qb = Qr + (long)(b*16+h)*2048*64;
  const unsigned short* Kb = Kr + (long)(b*16+h)*2048*64;
  const unsigned short* Vb = VT + (long)(b*16+h)*64*2048;
  const unsigned* bm = bmask + (long)b*2048*64;
  int r0 = ttile*64 + w*16;
  s16x8 aq[2];
#pragma unroll
  for(int ks=0;ks<2;ks++) aq[ks] = *(const s16x8*)(Qb + (long)(r0+fr)*64 + ks*32 + fg*8);
  float m[4], lsum[4];
  f32x4 accO[4];
#pragma unroll
  for(int r=0;r<4;r++){ m[r] = -1e30f; lsum[r]=0.f; }
#pragma unroll
  for(int nf=0;nf<4;nf++){ f32x4 z = {0.f,0.f,0.f,0.f}; accO[nf]=z; }

  for(int st=0; st<=ttile; st++){
    f32x4 sacc[4];
#pragma unroll
    for(int nf=0;nf<4;nf++){ f32x4 z = {0.f,0.f,0.f,0.f}; sacc[nf]=z; }
#pragma unroll
    for(int ks=0;ks<2;ks++)
#pragma unroll
      for(int nf=0;nf<4;nf++){
        s16x8 bk = *(const s16x8*)(Kb + (long)(st*64 + nf*16 + fr)*64 + ks*32 + fg*8);
        sacc[nf] = MFMA_BF16(aq[ks], bk, sacc[nf]);
      }
    float p[4][4]; // [nf][r]
#pragma unroll
    for(int r=0;r<4;r++){
      int trow = r0 + fg*4 + r;
      unsigned w0 = bm[(long)trow*64 + st*2];
      unsigned w1 = bm[(long)trow*64 + st*2+1];
      float vals[4];
      float vmax = -1e30f;
#pragma unroll
      for(int nf=0;nf<4;nf++){
        int sl = nf*16 + fr;
        unsigned word = (sl<32) ? w0 : w1;
        bool sel = (word>>(sl&31))&1u;
        vals[nf] = sel ? sacc[nf][r] : -1e30f;
        vmax = fmaxf(vmax, vals[nf]);
      }
#pragma unroll
      for(int off=1; off<16; off<<=1) vmax = fmaxf(vmax, __shfl_xor(vmax, off));
      float mnew = fmaxf(m[r], vmax);
      float sc = __expf(m[r]-mnew);
      float psum = 0.f;
#pragma unroll
      for(int nf=0;nf<4;nf++){
        float pv = (vals[nf] > -1e29f) ? __expf(vals[nf]-mnew) : 0.f;
        p[nf][r]=pv; psum += pv;
      }
#pragma unroll
      for(int off=1; off<16; off<<=1) psum += __shfl_xor(psum, off);
      lsum[r] = lsum[r]*sc + psum;
      m[r] = mnew;
#pragma unroll
      for(int nf=0;nf<4;nf++) accO[nf][r] *= sc;
    }
#pragma unroll
    for(int r=0;r<4;r++)
#pragma unroll
      for(int nf=0;nf<4;nf++)
        P[w][fg*4+r][nf*16+fr] = f2bf(p[nf][r]);
    __syncthreads();
#pragma unroll
    for(int ks=0;ks<2;ks++){
      s16x8 pa = *(const s16x8*)&P[w][fr][ks*32 + fg*8];
#pragma unroll
      for(int nf=0;nf<4;nf++){
        s16x8 bv = *(const s16x8*)(Vb + (long)(nf*16+fr)*2048 + st*64 + ks*32 + fg*8);
        accO[nf] = MFMA_BF16(pa, bv, accO[nf]);
      }
    }
    __syncthreads();
  }
#pragma unroll
  for(int r=0;r<4;r++){
    float inv = 1.0f/lsum[r];
    int trow = r0 + fg*4 + r;
#pragma unroll
    for(int nf=0;nf<4;nf++)
      attn[((long)b*2048 + trow)*1024 + h*64 + nf*16 + fr] = f2bf(accO[nf][r]*inv);
  }
}

// ---------- launcher ----------
extern "C" void kernel_launch(void* const* d_in, const int* in_sizes, int n_in,
                              void* d_out, int out_size, void* d_ws, size_t ws_size,
                              hipStream_t stream){
  (void)in_sizes; (void)n_in; (void)out_size; (void)ws_size;
  const float* x    = (const float*)d_in[0];
  const float* Wqkv = (const float*)d_in[1];
  const float* Wo   = (const float*)d_in[2];
  const float* Wqi  = (const float*)d_in[3];
  const float* Wki  = (const float*)d_in[4];
  const float* Wwi  = (const float*)d_in[5];
  const int*   pk   = (const int*)d_in[6];

  const int B=2, S=2048, D=1024, H=16;
  const long MS = (long)B*S;  // 4096

  char* ws = (char*)d_ws;
  size_t off = 0;
  auto alloc = [&](size_t bytes)->char*{
    char* p = ws + off; off = (off + bytes + 255) & ~(size_t)255; return p;
  };
  unsigned short* x_bf   = (unsigned short*)alloc(MS*D*2);
  unsigned short* wqkvT  = (unsigned short*)alloc((size_t)3*D*D*2);
  unsigned short* woT    = (unsigned short*)alloc((size_t)D*D*2);
  unsigned short* qkv_bf = (unsigned short*)alloc(MS*3*D*2);
  unsigned short* Qr     = (unsigned short*)alloc(MS*D*2);
  unsigned short* Kr     = (unsigned short*)alloc(MS*D*2);
  unsigned short* VTb    = (unsigned short*)alloc(MS*D*2);
  unsigned short* attnb  = (unsigned short*)alloc(MS*D*2);
  float* iq   = (float*)alloc(MS*256*4);
  float* ik   = (float*)alloc(MS*64*4);
  float* ikT  = (float*)alloc(MS*64*4);
  float* iw   = (float*)alloc(MS*4*4);
  float* cosT = (float*)alloc((size_t)S*32*4);
  float* sinT = (float*)alloc((size_t)S*32*4);
  unsigned* bmask = (unsigned*)alloc((size_t)B*S*64*4);

  // value-path inputs to bf16
  k_f32_to_bf16<<<4096,256,0,stream>>>(x, x_bf, (int)(MS*D));
  k_transpose<unsigned short><<<dim3(3*D/32, D/32, 1), dim3(32,8), 0, stream>>>(Wqkv, wqkvT, D, 3*D, 0, 0);
  k_transpose<unsigned short><<<dim3(D/32, D/32, 1), dim3(32,8), 0, stream>>>(Wo, woT, D, D, 0, 0);

  // indexer path (f32)
  k_gemm_f32<<<dim3(64,4),256,0,stream>>>(x, Wqi, iq, (int)MS, 256, D);
  k_gemm_f32<<<dim3(64,1),256,0,stream>>>(x, Wki, ik, (int)MS, 64, D);
  k_gemm_f32<<<dim3(64,1),256,0,stream>>>(x, Wwi, iw, (int)MS, 4, D);
  k_transpose<float><<<dim3(64/32, S/32, B), dim3(32,8), 0, stream>>>(ik, ikT, S, 64, (long)S*64, (long)S*64);
  k_topk<<<dim3(S,B),256,0,stream>>>(iq, ikT, iw, pk, bmask);

  // QKV + RoPE
  k_rope_tab<<<S*32/256,256,0,stream>>>(cosT, sinT);
  k_gemm_bf16<unsigned short><<<dim3(MS/128, 3*D/128), 256, 0, stream>>>(x_bf, wqkvT, qkv_bf, (int)MS, 3*D, D);
  k_rope_permute<<<dim3(S/64, H, B), 256, 0, stream>>>(qkv_bf, cosT, sinT, Qr, Kr, VTb);

  // masked attention + output projection
  k_attn<<<dim3(S/64, H, B), 256, 0, stream>>>(Qr, Kr, VTb, bmask, attnb);
  k_gemm_bf16<float><<<dim3(MS/128, D/128), 256, 0, stream>>>(attnb, woT, (float*)d_out, (int)MS, D, D);
}

// Round 2
// 632.050 us; speedup vs baseline: 1.3149x; 1.3149x over previous
//
#include <hip/hip_runtime.h>
#include <stdint.h>

// ---------- types & helpers ----------
typedef short s16x8 __attribute__((ext_vector_type(8)));
typedef float f32x4 __attribute__((ext_vector_type(4)));

#define MFMA_BF16(a,b,c) __builtin_amdgcn_mfma_f32_16x16x32_bf16((a),(b),(c),0,0,0)

static __device__ __forceinline__ float bf2f(unsigned short b){
  return __uint_as_float(((unsigned)b)<<16);
}
static __device__ __forceinline__ unsigned short f2bf(float f){
  unsigned u = __float_as_uint(f);
  unsigned r = u + 0x7FFFu + ((u>>16)&1u);
  return (unsigned short)(r>>16);
}
static __device__ __forceinline__ unsigned cvt_pk_bf16(float lo, float hi){
  unsigned r; asm("v_cvt_pk_bf16_f32 %0, %1, %2" : "=v"(r) : "v"(lo), "v"(hi)); return r;
}
static __device__ __forceinline__ void store_val(float* p, float v){ *p = v; }
static __device__ __forceinline__ void store_val(unsigned short* p, float v){ *p = f2bf(v); }

// order-preserving float->u32 (descending float == descending u32), +-0 canonicalized
static __device__ __forceinline__ unsigned ordf(float f){
  if (f == 0.0f) return 0x80000000u;
  unsigned u = __float_as_uint(f);
  return (u & 0x80000000u) ? ~u : (u | 0x80000000u);
}

typedef __attribute__((address_space(1))) const void g_void;
typedef __attribute__((address_space(3))) void l_void;
static __device__ __forceinline__ void gload_lds16(const void* g, void* lds){
  __builtin_amdgcn_global_load_lds((g_void*)g, (l_void*)lds, 16, 0, 0);
}

// ---------- elementwise convert f32 -> bf16 ----------
__global__ __launch_bounds__(256) void k_f32_to_bf16(const float* __restrict__ in,
                                                     unsigned short* __restrict__ out, int n){
  int i = blockIdx.x*256 + threadIdx.x;
  int stride = gridDim.x*256;
  for(; i<n; i+=stride) out[i] = f2bf(in[i]);
}

// ---------- transpose: in[R][C] f32 -> out[C][R] ----------
template<typename OT>
__global__ __launch_bounds__(256) void k_transpose(const float* __restrict__ in, OT* __restrict__ out,
                                                   int R, int C, long inStride, long outStride){
  __shared__ float tile[32][33];
  const float* inb = in + (long)blockIdx.z*inStride;
  OT* outb = out + (long)blockIdx.z*outStride;
  int tx = threadIdx.x, ty = threadIdx.y;        // block (32,8)
  int c0 = blockIdx.x*32, r0 = blockIdx.y*32;
#pragma unroll
  for(int j=0;j<4;j++) tile[ty+j*8][tx] = inb[(long)(r0+ty+j*8)*C + c0 + tx];
  __syncthreads();
#pragma unroll
  for(int j=0;j<4;j++) store_val(&outb[(long)(c0+ty+j*8)*R + r0 + tx], tile[tx][ty+j*8]);
}

// ---------- generic f32 GEMM ----------
__global__ __launch_bounds__(256) void k_gemm_f32(const float* __restrict__ A, const float* __restrict__ B,
                                                  float* __restrict__ C, int M, int N, int K){
  __shared__ float As[64][17];
  __shared__ float Bs[16][68];
  int tid = threadIdx.x;
  int tx = tid & 15, ty = tid >> 4;
  int m0 = blockIdx.x*64, n0 = blockIdx.y*64;
  float acc[4][4] = {};
  for(int k0=0; k0<K; k0+=16){
#pragma unroll
    for(int i=0;i<4;i++){
      int e = tid + i*256; int rr = e>>4, cc = e&15;
      As[rr][cc] = A[(long)(m0+rr)*K + k0 + cc];
    }
#pragma unroll
    for(int i=0;i<4;i++){
      int e = tid + i*256; int rr = e>>6, cc = e&63;
      int n = n0 + cc;
      Bs[rr][cc] = (n<N) ? B[(long)(k0+rr)*N + n] : 0.f;
    }
    __syncthreads();
#pragma unroll
    for(int kk=0;kk<16;kk++){
      float av[4], bv[4];
#pragma unroll
      for(int i=0;i<4;i++) av[i] = As[ty*4+i][kk];
#pragma unroll
      for(int j=0;j<4;j++) bv[j] = Bs[kk][tx*4+j];
#pragma unroll
      for(int i=0;i<4;i++)
#pragma unroll
        for(int j=0;j<4;j++) acc[i][j] = fmaf(av[i], bv[j], acc[i][j]);
    }
    __syncthreads();
  }
#pragma unroll
  for(int i=0;i<4;i++){
    int m = m0 + ty*4 + i;
#pragma unroll
    for(int j=0;j<4;j++){
      int n = n0 + tx*4 + j;
      if(n<N) C[(long)m*N + n] = acc[i][j];
    }
  }
}

// ---------- bf16 MFMA GEMM: C[M][N] = A[M][K] * BT[N][K]^T ----------
template<typename OT>
__global__ __launch_bounds__(256) void k_gemm_bf16(const unsigned short* __restrict__ A,
                                                   const unsigned short* __restrict__ BT,
                                                   OT* __restrict__ C, int M, int N, int K){
  __shared__ __align__(16) unsigned short As[128*32];
  __shared__ __align__(16) unsigned short Bs[128*32];
  int tid = threadIdx.x;
  int w = tid>>6, l = tid&63;
  int fr = l&15, fg = l>>4;
  int wm = (w>>1)*64, wn = (w&1)*64;
  long m0 = (long)blockIdx.x*128, n0 = (long)blockIdx.y*128;
  f32x4 acc[4][4];
#pragma unroll
  for(int i=0;i<4;i++)
#pragma unroll
    for(int j=0;j<4;j++){ f32x4 z = {0.f,0.f,0.f,0.f}; acc[i][j]=z; }

  for(int k0=0;k0<K;k0+=32){
    __syncthreads();
#pragma unroll
    for(int i=0;i<2;i++){
      int eo = (w*64 + l)*8 + i*2048;
      int rr = eo>>5, cc = eo&31;
      gload_lds16(A + (m0+rr)*K + k0 + cc, (char*)As + w*1024 + i*4096);
    }
#pragma unroll
    for(int i=0;i<2;i++){
      int eo = (w*64 + l)*8 + i*2048;
      int rr = eo>>5, cc = eo&31;
      gload_lds16(BT + (n0+rr)*K + k0 + cc, (char*)Bs + w*1024 + i*4096);
    }
    asm volatile("s_waitcnt vmcnt(0)" ::: "memory");
    __syncthreads();
    s16x8 af[4], bfr[4];
#pragma unroll
    for(int mf=0;mf<4;mf++) af[mf]  = *(const s16x8*)&As[(wm + mf*16 + fr)*32 + fg*8];
#pragma unroll
    for(int nf=0;nf<4;nf++) bfr[nf] = *(const s16x8*)&Bs[(wn + nf*16 + fr)*32 + fg*8];
#pragma unroll
    for(int mf=0;mf<4;mf++)
#pragma unroll
      for(int nf=0;nf<4;nf++)
        acc[mf][nf] = MFMA_BF16(af[mf], bfr[nf], acc[mf][nf]);
  }
#pragma unroll
  for(int mf=0;mf<4;mf++)
#pragma unroll
    for(int nf=0;nf<4;nf++)
#pragma unroll
      for(int r=0;r<4;r++){
        long m = m0 + wm + mf*16 + fg*4 + r;
        long n = n0 + wn + nf*16 + fr;
        store_val(&C[m*N + n], acc[mf][nf][r]);
      }
}

// ---------- RoPE tables ----------
__global__ __launch_bounds__(256) void k_rope_tab(float* __restrict__ cosT, float* __restrict__ sinT){
  int i = blockIdx.x*256 + threadIdx.x;   // 2048*32
  int t = i>>5, p = i&31;
  float theta = exp2f(-(float)p * (13.287712379549449f/32.0f)); // 10000^(-p/32)
  float ang = (float)t * theta;
  cosT[i] = cosf(ang);
  sinT[i] = sinf(ang);
}

// ---------- RoPE + head-permute ----------
__global__ __launch_bounds__(256) void k_rope_permute(const unsigned short* __restrict__ qkv,
                                                      const float* __restrict__ cosT, const float* __restrict__ sinT,
                                                      unsigned short* __restrict__ Qr, unsigned short* __restrict__ Kr,
                                                      unsigned short* __restrict__ VT){
  int st = blockIdx.x, h = blockIdx.y, b = blockIdx.z;
  int tid = threadIdx.x;
  __shared__ float vt[64][65];
  long rowbase = (long)b*2048 + st*64;
#pragma unroll
  for(int part=0; part<2; part++){
    const int colbase = part*1024 + h*64;
    unsigned short* outp = part ? Kr : Qr;
    float prescale = part ? 1.0f : 0.125f;
#pragma unroll
    for(int i=0;i<8;i++){
      int e = tid + i*256;            // 64 rows x 32 pairs
      int row = e>>5, p = e&31;
      long s = (long)st*64 + row;
      const unsigned short* src = qkv + (rowbase+row)*3072 + colbase + 2*p;
      float x0 = bf2f(src[0]), x1 = bf2f(src[1]);
      float c = cosT[s*32+p], sn = sinT[s*32+p];
      float y0 = (x0*c - x1*sn)*prescale;
      float y1 = (x1*c + x0*sn)*prescale;
      unsigned short* dst = outp + ((long)(b*16+h)*2048 + s)*64 + 2*p;
      dst[0] = f2bf(y0); dst[1] = f2bf(y1);
    }
  }
#pragma unroll
  for(int i=0;i<16;i++){
    int e = tid + i*256;
    int row = e>>6, col = e&63;
    vt[col][row] = bf2f(qkv[(rowbase+row)*3072 + 2048 + h*64 + col]);
  }
  __syncthreads();
#pragma unroll
  for(int i=0;i<16;i++){
    int e = tid + i*256;
    int d = e>>6, scol = e&63;
    VT[((long)(b*16+h)*64 + d)*2048 + (long)st*64 + scol] = f2bf(vt[d][scol]);
  }
}

// ---------- per-row index scores + exact top-k (stable ties) -> bitmask ----------
// Block handles rows t1=blockIdx.x and t2=2047-blockIdx.x (load balance).
__global__ __launch_bounds__(256) void k_topk(const float* __restrict__ iq, const float* __restrict__ ikT,
                                              const float* __restrict__ iw, const int* __restrict__ pk,
                                              unsigned* __restrict__ bmask){
  int b = blockIdx.y;
  int tid = threadIdx.x;
  int k = pk[0];
  __shared__ float siq[256];
  __shared__ float siw[4];
  __shared__ unsigned su[2048];
  __shared__ unsigned hist[256];
  __shared__ unsigned scan[256];
  __shared__ unsigned words[64];
  __shared__ unsigned sh_b[2];
  const int s0 = tid*8;

  for(int rp=0; rp<2; rp++){
    int t = rp ? (2047 - (int)blockIdx.x) : (int)blockIdx.x;
    long row = (long)b*2048 + t;
    siq[tid] = iq[row*256 + tid];
    if(tid<4) siw[tid] = iw[row*4 + tid];
    __syncthreads();

    if (s0 <= t){
      float acc[4][8];
#pragma unroll
      for(int h=0;h<4;h++)
#pragma unroll
        for(int j=0;j<8;j++) acc[h][j]=0.f;
      const float* ikb = ikT + (long)b*64*2048;
      for(int d=0;d<64;d++){
        const float* prow = ikb + (long)d*2048 + s0;
        float4 v0 = *(const float4*)prow;
        float4 v1 = *(const float4*)(prow+4);
        float ikv[8] = {v0.x,v0.y,v0.z,v0.w,v1.x,v1.y,v1.z,v1.w};
#pragma unroll
        for(int h=0;h<4;h++){
          float q = siq[h*64+d];
#pragma unroll
          for(int j=0;j<8;j++) acc[h][j] = fmaf(q, ikv[j], acc[h][j]);
        }
      }
#pragma unroll
      for(int j=0;j<8;j++){
        int s = s0+j;
        if(s<=t){
          float I = 0.f;
#pragma unroll
          for(int h=0;h<4;h++) I += siw[h]*fmaxf(acc[h][j],0.f);
          su[s] = ordf(I);
        }
      }
    }
    __syncthreads();

    unsigned thr = 0; int kk = 0;
    bool allsel = (t+1 <= k);
    if (!allsel){
      unsigned prefix=0, msk=0;
      kk = k;
      for(int shift=24; shift>=0; shift-=8){
        hist[tid]=0; __syncthreads();
        if(s0<=t){
          for(int j=0;j<8;j++){
            int s=s0+j; if(s>t) break;
            unsigned u=su[s];
            if((u&msk)==prefix) atomicAdd(&hist[(u>>shift)&255],1u);
          }
        }
        __syncthreads();
        // parallel threshold-bin search: suffix sums over bins (descending)
        scan[tid] = hist[255-tid];
        __syncthreads();
        for(int off2=1; off2<256; off2<<=1){
          unsigned v = (tid>=off2) ? scan[tid-off2] : 0u;
          __syncthreads();
          scan[tid]+=v;
          __syncthreads();
        }
        {
          unsigned incl = scan[255-tid];          // sum_{v>=tid} hist[v]
          unsigned cb   = incl - hist[tid];        // sum_{v> tid} hist[v]
          if (cb < (unsigned)kk && incl >= (unsigned)kk){ sh_b[0]=(unsigned)tid; sh_b[1]=(unsigned)kk-cb; }
        }
        __syncthreads();
        prefix |= sh_b[0]<<shift; msk |= 255u<<shift; kk = (int)sh_b[1];
        __syncthreads();
      }
      thr = prefix;
    }

    unsigned gtb=0, eqb=0;
    if (s0 <= t){
      for(int j=0;j<8;j++){
        int s=s0+j; if(s>t) break;
        if(allsel){ gtb |= 1u<<j; }
        else{
          unsigned u=su[s];
          if(u>thr) gtb |= 1u<<j;
          else if(u==thr) eqb |= 1u<<j;
        }
      }
    }
    int cnt = __popc(eqb);
    scan[tid]=(unsigned)cnt; __syncthreads();
    for(int off2=1; off2<256; off2<<=1){
      unsigned v = (tid>=off2) ? scan[tid-off2] : 0u;
      __syncthreads();
      scan[tid]+=v;
      __syncthreads();
    }
    int excl = (int)scan[tid]-cnt;
    unsigned bits = gtb;
    if(eqb){
      int seen=0;
      for(int j=0;j<8;j++) if((eqb>>j)&1u){ if(excl+seen < kk) bits |= 1u<<j; seen++; }
    }
    if(tid<64) words[tid]=0;
    __syncthreads();
    if(bits) atomicOr(&words[tid>>2], bits << ((tid&3)*8));
    __syncthreads();
    if(tid<64) bmask[row*64 + tid] = words[tid];
    __syncthreads();
  }
}

// ---------- masked flash attention (swapped-QK, barrier-free, balanced) ----------
// Block x in 0..15 handles ttiles {x, 31-x} (33 tile-iters each -> perfect balance).
__global__ __launch_bounds__(256) void k_attn(const unsigned short* __restrict__ Qr,
                                              const unsigned short* __restrict__ Kr,
                                              const unsigned short* __restrict__ VT,
                                              const unsigned* __restrict__ bmask,
                                              unsigned short* __restrict__ attn){
  int xb = blockIdx.x, h = blockIdx.y, b = blockIdx.z;
  int tid = threadIdx.x, w = tid>>6, l = tid&63;
  int fr = l&15, fg = l>>4;
  __shared__ __align__(16) unsigned short P[4][16][72];   // per-wave private slice
  const unsigned short* Qb = Qr + (long)(b*16+h)*2048*64;
  const unsigned short* Kb = Kr + (long)(b*16+h)*2048*64;
  const unsigned short* Vb = VT + (long)(b*16+h)*64*2048;
  const unsigned* bm = bmask + (long)b*2048*64;

#pragma unroll 1
  for(int pass=0; pass<2; pass++){
    int ttile = pass ? (31-xb) : xb;
    int r0 = ttile*64 + w*16;
    s16x8 aq[2];
#pragma unroll
    for(int ks=0;ks<2;ks++) aq[ks] = *(const s16x8*)(Qb + (long)(r0+fr)*64 + ks*32 + fg*8);
    const unsigned* bmrow = bm + (long)(r0+fr)*64;
    float mrow = -1e30f, lrow = 0.f;
    f32x4 accO[4];
#pragma unroll
    for(int nf=0;nf<4;nf++){ f32x4 z = {0.f,0.f,0.f,0.f}; accO[nf]=z; }

    for(int st=0; st<=ttile; st++){
      unsigned w0 = bmrow[st*2], w1 = bmrow[st*2+1];
      f32x4 sacc[4];
#pragma unroll
      for(int nf=0;nf<4;nf++){ f32x4 z = {0.f,0.f,0.f,0.f}; sacc[nf]=z; }
      // swapped QK^T: D[s][q] -> lane holds q=fr, k = nf*16 + fg*4 + r
#pragma unroll
      for(int ks=0;ks<2;ks++)
#pragma unroll
        for(int nf=0;nf<4;nf++){
          s16x8 bk = *(const s16x8*)(Kb + (long)(st*64 + nf*16 + fr)*64 + ks*32 + fg*8);
          sacc[nf] = MFMA_BF16(bk, aq[ks], sacc[nf]);
        }
      float p[4][4];
      float vmax = -1e30f;
#pragma unroll
      for(int nf=0;nf<4;nf++)
#pragma unroll
        for(int r=0;r<4;r++){
          int sl = nf*16 + fg*4 + r;
          unsigned word = (sl<32) ? w0 : w1;
          bool sel = (word>>(sl&31))&1u;
          float v = sel ? sacc[nf][r] : -1e30f;
          p[nf][r] = v;
          vmax = fmaxf(vmax, v);
        }
      vmax = fmaxf(vmax, __shfl_xor(vmax,16));
      vmax = fmaxf(vmax, __shfl_xor(vmax,32));
      float mnew = fmaxf(mrow, vmax);
      float sc = __expf(mrow - mnew);
      float psum = 0.f;
#pragma unroll
      for(int nf=0;nf<4;nf++)
#pragma unroll
        for(int r=0;r<4;r++){
          float v = p[nf][r];
          float e = (v > -1e29f) ? __expf(v - mnew) : 0.f;
          p[nf][r] = e; psum += e;
        }
      psum += __shfl_xor(psum,16);
      psum += __shfl_xor(psum,32);
      lrow = lrow*sc + psum; mrow = mnew;
      // P -> per-wave LDS (packed bf16 pairs), no barrier (same-wave DS order)
#pragma unroll
      for(int nf=0;nf<4;nf++){
        *(unsigned*)&P[w][fr][nf*16 + fg*4 + 0] = cvt_pk_bf16(p[nf][0], p[nf][1]);
        *(unsigned*)&P[w][fr][nf*16 + fg*4 + 2] = cvt_pk_bf16(p[nf][2], p[nf][3]);
      }
      // broadcast sc to PV accumulator layout (rows q = fg*4+r)
      float scv[4];
#pragma unroll
      for(int r=0;r<4;r++) scv[r] = __shfl(sc, fg*4 + r);
#pragma unroll
      for(int nf=0;nf<4;nf++)
#pragma unroll
        for(int r=0;r<4;r++) accO[nf][r] *= scv[r];
      __builtin_amdgcn_sched_barrier(0);
#pragma unroll
      for(int ks=0;ks<2;ks++){
        s16x8 pa = *(const s16x8*)&P[w][fr][ks*32 + fg*8];
#pragma unroll
        for(int nf=0;nf<4;nf++){
          s16x8 bv = *(const s16x8*)(Vb + (long)(nf*16+fr)*2048 + st*64 + ks*32 + fg*8);
          accO[nf] = MFMA_BF16(pa, bv, accO[nf]);
        }
      }
    }
    float linv[4];
#pragma unroll
    for(int r=0;r<4;r++) linv[r] = 1.0f/__shfl(lrow, fg*4 + r);
#pragma unroll
    for(int r=0;r<4;r++){
      int trow = r0 + fg*4 + r;
#pragma unroll
      for(int nf=0;nf<4;nf++)
        attn[((long)b*2048 + trow)*1024 + h*64 + nf*16 + fr] = f2bf(accO[nf][r]*linv[r]);
    }
  }
}

// ---------- launcher ----------
extern "C" void kernel_launch(void* const* d_in, const int* in_sizes, int n_in,
                              void* d_out, int out_size, void* d_ws, size_t ws_size,
                              hipStream_t stream){
  (void)in_sizes; (void)n_in; (void)out_size; (void)ws_size;
  const float* x    = (const float*)d_in[0];
  const float* Wqkv = (const float*)d_in[1];
  const float* Wo   = (const float*)d_in[2];
  const float* Wqi  = (const float*)d_in[3];
  const float* Wki  = (const float*)d_in[4];
  const float* Wwi  = (const float*)d_in[5];
  const int*   pk   = (const int*)d_in[6];

  const int B=2, S=2048, D=1024, H=16;
  const long MS = (long)B*S;  // 4096

  char* ws = (char*)d_ws;
  size_t off = 0;
  auto alloc = [&](size_t bytes)->char*{
    char* p = ws + off; off = (off + bytes + 255) & ~(size_t)255; return p;
  };
  unsigned short* x_bf   = (unsigned short*)alloc(MS*D*2);
  unsigned short* wqkvT  = (unsigned short*)alloc((size_t)3*D*D*2);
  unsigned short* woT    = (unsigned short*)alloc((size_t)D*D*2);
  unsigned short* qkv_bf = (unsigned short*)alloc(MS*3*D*2);
  unsigned short* Qr     = (unsigned short*)alloc(MS*D*2);
  unsigned short* Kr     = (unsigned short*)alloc(MS*D*2);
  unsigned short* VTb    = (unsigned short*)alloc(MS*D*2);
  unsigned short* attnb  = (unsigned short*)alloc(MS*D*2);
  float* iq   = (float*)alloc(MS*256*4);
  float* ik   = (float*)alloc(MS*64*4);
  float* ikT  = (float*)alloc(MS*64*4);
  float* iw   = (float*)alloc(MS*4*4);
  float* cosT = (float*)alloc((size_t)S*32*4);
  float* sinT = (float*)alloc((size_t)S*32*4);
  unsigned* bmask = (unsigned*)alloc((size_t)B*S*64*4);

  // value-path inputs to bf16
  k_f32_to_bf16<<<4096,256,0,stream>>>(x, x_bf, (int)(MS*D));
  k_transpose<unsigned short><<<dim3(3*D/32, D/32, 1), dim3(32,8), 0, stream>>>(Wqkv, wqkvT, D, 3*D, 0, 0);
  k_transpose<unsigned short><<<dim3(D/32, D/32, 1), dim3(32,8), 0, stream>>>(Wo, woT, D, D, 0, 0);

  // indexer path (f32)
  k_gemm_f32<<<dim3(64,4),256,0,stream>>>(x, Wqi, iq, (int)MS, 256, D);
  k_gemm_f32<<<dim3(64,1),256,0,stream>>>(x, Wki, ik, (int)MS, 64, D);
  k_gemm_f32<<<dim3(64,1),256,0,stream>>>(x, Wwi, iw, (int)MS, 4, D);
  k_transpose<float><<<dim3(64/32, S/32, B), dim3(32,8), 0, stream>>>(ik, ikT, S, 64, (long)S*64, (long)S*64);
  k_topk<<<dim3(S/2,B),256,0,stream>>>(iq, ikT, iw, pk, bmask);

  // QKV + RoPE
  k_rope_tab<<<S*32/256,256,0,stream>>>(cosT, sinT);
  k_gemm_bf16<unsigned short><<<dim3(MS/128, 3*D/128), 256, 0, stream>>>(x_bf, wqkvT, qkv_bf, (int)MS, 3*D, D);
  k_rope_permute<<<dim3(S/64, H, B), 256, 0, stream>>>(qkv_bf, cosT, sinT, Qr, Kr, VTb);

  // masked attention + output projection
  k_attn<<<dim3(16, H, B), 256, 0, stream>>>(Qr, Kr, VTb, bmask, attnb);
  k_gemm_bf16<float><<<dim3(MS/128, D/128), 256, 0, stream>>>(attnb, woT, (float*)d_out, (int)MS, D, D);
}

// Round 3
// 491.531 us; speedup vs baseline: 1.6909x; 1.2859x over previous
//
#include <hip/hip_runtime.h>
#include <stdint.h>

// ---------- types & helpers ----------
typedef short s16x8 __attribute__((ext_vector_type(8)));
typedef float f32x4 __attribute__((ext_vector_type(4)));

#define MFMA_BF16(a,b,c) __builtin_amdgcn_mfma_f32_16x16x32_bf16((a),(b),(c),0,0,0)

static __device__ __forceinline__ float bf2f(unsigned short b){
  return __uint_as_float(((unsigned)b)<<16);
}
static __device__ __forceinline__ unsigned short f2bf(float f){
  unsigned u = __float_as_uint(f);
  unsigned r = u + 0x7FFFu + ((u>>16)&1u);
  return (unsigned short)(r>>16);
}
static __device__ __forceinline__ unsigned cvt_pk_bf16(float lo, float hi){
  unsigned r; asm("v_cvt_pk_bf16_f32 %0, %1, %2" : "=v"(r) : "v"(lo), "v"(hi)); return r;
}
static __device__ __forceinline__ void store_val(float* p, float v){ *p = v; }
static __device__ __forceinline__ void store_val(unsigned short* p, float v){ *p = f2bf(v); }

// order-preserving float->u32 (descending float == descending u32), +-0 canonicalized
static __device__ __forceinline__ unsigned ordf(float f){
  if (f == 0.0f) return 0x80000000u;
  unsigned u = __float_as_uint(f);
  return (u & 0x80000000u) ? ~u : (u | 0x80000000u);
}

typedef __attribute__((address_space(1))) const void g_void;
typedef __attribute__((address_space(3))) void l_void;
static __device__ __forceinline__ void gload_lds16(const void* g, void* lds){
  __builtin_amdgcn_global_load_lds((g_void*)g, (l_void*)lds, 16, 0, 0);
}

// ---------- elementwise convert f32 -> bf16 ----------
__global__ __launch_bounds__(256) void k_f32_to_bf16(const float* __restrict__ in,
                                                     unsigned short* __restrict__ out, int n){
  int i = blockIdx.x*256 + threadIdx.x;
  int stride = gridDim.x*256;
  for(; i<n; i+=stride) out[i] = f2bf(in[i]);
}

// ---------- pack Wqi|Wki|Wwi into Bcat [1024][324] ----------
__global__ __launch_bounds__(256) void k_pack_b(const float* __restrict__ Wqi, const float* __restrict__ Wki,
                                                const float* __restrict__ Wwi, float* __restrict__ Bcat){
  int i = blockIdx.x*256 + threadIdx.x;
  if(i >= 1024*324) return;
  int kk = i/324, j = i - kk*324;
  float v = (j<256) ? Wqi[kk*256+j] : (j<320) ? Wki[kk*64 + (j-256)] : Wwi[kk*4 + (j-320)];
  Bcat[i] = v;
}

// ---------- transpose: in[R][C] (row stride inRS) f32 -> out[C][R] ----------
template<typename OT>
__global__ __launch_bounds__(256) void k_transpose(const float* __restrict__ in, OT* __restrict__ out,
                                                   int R, int C, int inRS, long zIn, long zOut){
  __shared__ float tile[32][33];
  const float* inb = in + (long)blockIdx.z*zIn;
  OT* outb = out + (long)blockIdx.z*zOut;
  int tx = threadIdx.x, ty = threadIdx.y;        // block (32,8)
  int c0 = blockIdx.x*32, r0 = blockIdx.y*32;
#pragma unroll
  for(int j=0;j<4;j++) tile[ty+j*8][tx] = inb[(long)(r0+ty+j*8)*inRS + c0 + tx];
  __syncthreads();
#pragma unroll
  for(int j=0;j<4;j++) store_val(&outb[(long)(c0+ty+j*8)*R + r0 + tx], tile[tx][ty+j*8]);
}

// ---------- generic f32 GEMM ----------
__global__ __launch_bounds__(256) void k_gemm_f32(const float* __restrict__ A, const float* __restrict__ B,
                                                  float* __restrict__ C, int M, int N, int K){
  __shared__ float As[64][17];
  __shared__ float Bs[16][68];
  int tid = threadIdx.x;
  int tx = tid & 15, ty = tid >> 4;
  int m0 = blockIdx.x*64, n0 = blockIdx.y*64;
  float acc[4][4] = {};
  for(int k0=0; k0<K; k0+=16){
#pragma unroll
    for(int i=0;i<4;i++){
      int e = tid + i*256; int rr = e>>4, cc = e&15;
      As[rr][cc] = A[(long)(m0+rr)*K + k0 + cc];
    }
#pragma unroll
    for(int i=0;i<4;i++){
      int e = tid + i*256; int rr = e>>6, cc = e&63;
      int n = n0 + cc;
      Bs[rr][cc] = (n<N) ? B[(long)(k0+rr)*N + n] : 0.f;
    }
    __syncthreads();
#pragma unroll
    for(int kk=0;kk<16;kk++){
      float av[4], bv[4];
#pragma unroll
      for(int i=0;i<4;i++) av[i] = As[ty*4+i][kk];
#pragma unroll
      for(int j=0;j<4;j++) bv[j] = Bs[kk][tx*4+j];
#pragma unroll
      for(int i=0;i<4;i++)
#pragma unroll
        for(int j=0;j<4;j++) acc[i][j] = fmaf(av[i], bv[j], acc[i][j]);
    }
    __syncthreads();
  }
#pragma unroll
  for(int i=0;i<4;i++){
    int m = m0 + ty*4 + i;
#pragma unroll
    for(int j=0;j<4;j++){
      int n = n0 + tx*4 + j;
      if(n<N) C[(long)m*N + n] = acc[i][j];
    }
  }
}

// ---------- bf16 MFMA GEMM: C[M][N] = A[M][K] * BT[N][K]^T ----------
template<typename OT>
__global__ __launch_bounds__(256) void k_gemm_bf16(const unsigned short* __restrict__ A,
                                                   const unsigned short* __restrict__ BT,
                                                   OT* __restrict__ C, int M, int N, int K){
  __shared__ __align__(16) unsigned short As[128*32];
  __shared__ __align__(16) unsigned short Bs[128*32];
  int tid = threadIdx.x;
  int w = tid>>6, l = tid&63;
  int fr = l&15, fg = l>>4;
  int wm = (w>>1)*64, wn = (w&1)*64;
  long m0 = (long)blockIdx.x*128, n0 = (long)blockIdx.y*128;
  f32x4 acc[4][4];
#pragma unroll
  for(int i=0;i<4;i++)
#pragma unroll
    for(int j=0;j<4;j++){ f32x4 z = {0.f,0.f,0.f,0.f}; acc[i][j]=z; }

  for(int k0=0;k0<K;k0+=32){
    __syncthreads();
#pragma unroll
    for(int i=0;i<2;i++){
      int eo = (w*64 + l)*8 + i*2048;
      int rr = eo>>5, cc = eo&31;
      gload_lds16(A + (m0+rr)*K + k0 + cc, (char*)As + w*1024 + i*4096);
    }
#pragma unroll
    for(int i=0;i<2;i++){
      int eo = (w*64 + l)*8 + i*2048;
      int rr = eo>>5, cc = eo&31;
      gload_lds16(BT + (n0+rr)*K + k0 + cc, (char*)Bs + w*1024 + i*4096);
    }
    asm volatile("s_waitcnt vmcnt(0)" ::: "memory");
    __syncthreads();
    s16x8 af[4], bfr[4];
#pragma unroll
    for(int mf=0;mf<4;mf++) af[mf]  = *(const s16x8*)&As[(wm + mf*16 + fr)*32 + fg*8];
#pragma unroll
    for(int nf=0;nf<4;nf++) bfr[nf] = *(const s16x8*)&Bs[(wn + nf*16 + fr)*32 + fg*8];
#pragma unroll
    for(int mf=0;mf<4;mf++)
#pragma unroll
      for(int nf=0;nf<4;nf++)
        acc[mf][nf] = MFMA_BF16(af[mf], bfr[nf], acc[mf][nf]);
  }
#pragma unroll
  for(int mf=0;mf<4;mf++)
#pragma unroll
    for(int nf=0;nf<4;nf++)
#pragma unroll
      for(int r=0;r<4;r++){
        long m = m0 + wm + mf*16 + fg*4 + r;
        long n = n0 + wn + nf*16 + fr;
        store_val(&C[m*N + n], acc[mf][nf][r]);
      }
}

// ---------- RoPE tables ----------
__global__ __launch_bounds__(256) void k_rope_tab(float* __restrict__ cosT, float* __restrict__ sinT){
  int i = blockIdx.x*256 + threadIdx.x;   // 2048*32
  int t = i>>5, p = i&31;
  float theta = exp2f(-(float)p * (13.287712379549449f/32.0f)); // 10000^(-p/32)
  float ang = (float)t * theta;
  cosT[i] = cosf(ang);
  sinT[i] = sinf(ang);
}

// ---------- RoPE + head-permute; Q prescaled by 0.125*log2(e) (exp2 domain) ----------
__global__ __launch_bounds__(256) void k_rope_permute(const unsigned short* __restrict__ qkv,
                                                      const float* __restrict__ cosT, const float* __restrict__ sinT,
                                                      unsigned short* __restrict__ Qr, unsigned short* __restrict__ Kr,
                                                      unsigned short* __restrict__ VT){
  int st = blockIdx.x, h = blockIdx.y, b = blockIdx.z;
  int tid = threadIdx.x;
  __shared__ float vt[64][65];
  long rowbase = (long)b*2048 + st*64;
#pragma unroll
  for(int part=0; part<2; part++){
    const int colbase = part*1024 + h*64;
    unsigned short* outp = part ? Kr : Qr;
    float prescale = part ? 1.0f : 0.18033688011112042f;   // 0.125 * log2(e)
#pragma unroll
    for(int i=0;i<8;i++){
      int e = tid + i*256;            // 64 rows x 32 pairs
      int row = e>>5, p = e&31;
      long s = (long)st*64 + row;
      const unsigned short* src = qkv + (rowbase+row)*3072 + colbase + 2*p;
      float x0 = bf2f(src[0]), x1 = bf2f(src[1]);
      float c = cosT[s*32+p], sn = sinT[s*32+p];
      float y0 = (x0*c - x1*sn)*prescale;
      float y1 = (x1*c + x0*sn)*prescale;
      unsigned short* dst = outp + ((long)(b*16+h)*2048 + s)*64 + 2*p;
      dst[0] = f2bf(y0); dst[1] = f2bf(y1);
    }
  }
#pragma unroll
  for(int i=0;i<16;i++){
    int e = tid + i*256;
    int row = e>>6, col = e&63;
    vt[col][row] = bf2f(qkv[(rowbase+row)*3072 + 2048 + h*64 + col]);
  }
  __syncthreads();
#pragma unroll
  for(int i=0;i<16;i++){
    int e = tid + i*256;
    int d = e>>6, scol = e&63;
    VT[((long)(b*16+h)*64 + d)*2048 + (long)st*64 + scol] = f2bf(vt[d][scol]);
  }
}

// ---------- per-row index scores + exact top-k (stable ties) -> bitmask ----------
// Block handles rows t1=blockIdx.x, t2=2047-blockIdx.x. Wave-level scans (barrier-light).
__global__ __launch_bounds__(256) void k_topk(const float* __restrict__ iqkw, const int* __restrict__ pk,
                                              unsigned* __restrict__ bmask){
  int b = blockIdx.y;
  int tid = threadIdx.x;
  int w = tid>>6, lane = tid&63;
  int k = pk[0];
  __shared__ float siq[256];
  __shared__ float siw[4];
  __shared__ unsigned su[2048];
  __shared__ unsigned hist4[4][256];
  __shared__ unsigned chunk[4];
  __shared__ unsigned words[64];
  __shared__ unsigned sh_b[2];
  const int s0 = tid*8;
  const float* ikb = iqkw + (long)b*2048*324 + 256;   // ik columns live at offset 256, but we use transposed copy

  (void)ikb;
  for(int rp=0; rp<2; rp++){
    int t = rp ? (2047 - (int)blockIdx.x) : (int)blockIdx.x;
    long row = (long)b*2048 + t;
    siq[tid] = iqkw[row*324 + tid];
    if(tid<4) siw[tid] = iqkw[row*324 + 320 + tid];
    __syncthreads();

    if (s0 <= t){
      float acc[4][8];
#pragma unroll
      for(int h=0;h<4;h++)
#pragma unroll
        for(int j=0;j<8;j++) acc[h][j]=0.f;
      const float* ikTb = (const float*)nullptr;
      (void)ikTb;
      extern __shared__ char _dummy[]; (void)_dummy;
      const float* ikT = 0; (void)ikT;
      // loads come from global ikT buffer passed via su trick? -- use global pointer param below
      ;
    }
    __syncthreads();
    // NOTE: score phase moved below using global ikT (see k_topk2 actual body)
    (void)w; (void)lane; (void)chunk; (void)hist4; (void)words; (void)sh_b; (void)su; (void)siw; (void)siq; (void)k;
    break;
  }
}

// Real top-k kernel (the one launched). Separate to keep signature clean.
__global__ __launch_bounds__(256) void k_topk2(const float* __restrict__ iqkw, const float* __restrict__ ikT,
                                               const int* __restrict__ pk, unsigned* __restrict__ bmask){
  int b = blockIdx.y;
  int tid = threadIdx.x;
  int w = tid>>6, lane = tid&63;
  int k = pk[0];
  __shared__ float siq[256];
  __shared__ float siw[4];
  __shared__ unsigned su[2048];
  __shared__ unsigned hist4[4][256];
  __shared__ unsigned chunk[4];
  __shared__ unsigned words[64];
  __shared__ unsigned sh_b[2];
  const int s0 = tid*8;

  for(int rp=0; rp<2; rp++){
    int t = rp ? (2047 - (int)blockIdx.x) : (int)blockIdx.x;
    long row = (long)b*2048 + t;
    siq[tid] = iqkw[row*324 + tid];
    if(tid<4) siw[tid] = iqkw[row*324 + 320 + tid];
    __syncthreads();

    // ---- scores for s in [s0, s0+8) ----
    if (s0 <= t){
      float acc[4][8];
#pragma unroll
      for(int h=0;h<4;h++)
#pragma unroll
        for(int j=0;j<8;j++) acc[h][j]=0.f;
      const float* ikb = ikT + (long)b*64*2048;
      for(int d=0;d<64;d++){
        const float* prow = ikb + (long)d*2048 + s0;
        float4 v0 = *(const float4*)prow;
        float4 v1 = *(const float4*)(prow+4);
        float ikv[8] = {v0.x,v0.y,v0.z,v0.w,v1.x,v1.y,v1.z,v1.w};
#pragma unroll
        for(int h=0;h<4;h++){
          float q = siq[h*64+d];
#pragma unroll
          for(int j=0;j<8;j++) acc[h][j] = fmaf(q, ikv[j], acc[h][j]);
        }
      }
#pragma unroll
      for(int j=0;j<8;j++){
        int s = s0+j;
        if(s<=t){
          float I = 0.f;
#pragma unroll
          for(int h=0;h<4;h++) I += siw[h]*fmaxf(acc[h][j],0.f);
          su[s] = ordf(I);
        }
      }
    }
    __syncthreads();

    // ---- exact top-k threshold via 4x 8-bit radix, wave-level scans ----
    unsigned thr = 0; int kk = 0;
    bool allsel = (t+1 <= k);
    if (!allsel){
      unsigned prefix=0, msk=0;
      kk = k;
      for(int shift=24; shift>=0; shift-=8){
#pragma unroll
        for(int i=0;i<4;i++) hist4[i][tid]=0;
        __syncthreads();
        if(s0<=t){
          for(int j=0;j<8;j++){
            int s=s0+j; if(s>t) break;
            unsigned u=su[s];
            if((u&msk)==prefix) atomicAdd(&hist4[w][(u>>shift)&255],1u);
          }
        }
        __syncthreads();
        unsigned hv = hist4[0][tid]+hist4[1][tid]+hist4[2][tid]+hist4[3][tid];
        // wave suffix-scan over the 64 bins of this wave's chunk (bin = tid)
        unsigned sfx = hv;
#pragma unroll
        for(int off=1; off<64; off<<=1){
          unsigned tmp = __shfl_down(sfx, off);
          if(lane < 64-off) sfx += tmp;
        }
        if(lane==0) chunk[w] = sfx;
        __syncthreads();
        unsigned above = 0;
#pragma unroll
        for(int c=0;c<4;c++) if(c>w) above += chunk[c];
        unsigned incl = sfx + above;     // count of elems with bin >= tid
        unsigned cb   = incl - hv;       // count with bin > tid
        if(cb < (unsigned)kk && incl >= (unsigned)kk){ sh_b[0]=(unsigned)tid; sh_b[1]=(unsigned)kk-cb; }
        __syncthreads();
        prefix |= sh_b[0]<<shift; msk |= 255u<<shift; kk = (int)sh_b[1];
        __syncthreads();
      }
      thr = prefix;
    }

    // ---- emit bits: score>thr always; ==thr first kk in index order ----
    unsigned gtb=0, eqb=0;
    if (s0 <= t){
      for(int j=0;j<8;j++){
        int s=s0+j; if(s>t) break;
        if(allsel){ gtb |= 1u<<j; }
        else{
          unsigned u=su[s];
          if(u>thr) gtb |= 1u<<j;
          else if(u==thr) eqb |= 1u<<j;
        }
      }
    }
    int cnt = __popc(eqb);
    // block exclusive-prefix of cnt: wave inclusive prefix + chunk offsets
    unsigned pfx = (unsigned)cnt;
#pragma unroll
    for(int off=1; off<64; off<<=1){
      unsigned tmp = __shfl_up(pfx, off);
      if(lane >= off) pfx += tmp;
    }
    if(lane==63) chunk[w] = pfx;
    __syncthreads();
    unsigned below = 0;
#pragma unroll
    for(int c=0;c<4;c++) if(c<w) below += chunk[c];
    int excl = (int)(pfx - (unsigned)cnt + below);
    unsigned bits = gtb;
    if(eqb){
      int seen=0;
      for(int j=0;j<8;j++) if((eqb>>j)&1u){ if(excl+seen < kk) bits |= 1u<<j; seen++; }
    }
    if(tid<64) words[tid]=0;
    __syncthreads();
    if(bits) atomicOr(&words[tid>>2], bits << ((tid&3)*8));
    __syncthreads();
    if(tid<64) bmask[row*64 + tid] = words[tid];
    __syncthreads();
  }
}

// ---------- masked flash attention, split-KV x2 partials ----------
// grid (32,16,2): x = pair*2 + kp ; block does ttiles {pair, 31-pair}, KV-half kp. exp2 domain.
__global__ __launch_bounds__(256) void k_attn_part(const unsigned short* __restrict__ Qr,
                                                   const unsigned short* __restrict__ Kr,
                                                   const unsigned short* __restrict__ VT,
                                                   const unsigned* __restrict__ bmask,
                                                   unsigned short* __restrict__ pO,
                                                   float2* __restrict__ pML){
  int xb = blockIdx.x, h = blockIdx.y, b = blockIdx.z;
  int pair = xb>>1, kp = xb&1;
  int tid = threadIdx.x, w = tid>>6, l = tid&63;
  int fr = l&15, fg = l>>4;
  __shared__ __align__(16) unsigned short P[4][16][72];   // per-wave private slice
  const unsigned short* Qb = Qr + (long)(b*16+h)*2048*64;
  const unsigned short* Kb = Kr + (long)(b*16+h)*2048*64;
  const unsigned short* Vb = VT + (long)(b*16+h)*64*2048;
  const unsigned* bm = bmask + (long)b*2048*64;
  long pbase = ((long)(b*16+h)*2 + kp)*2048;

#pragma unroll 1
  for(int pass=0; pass<2; pass++){
    int T = pass ? (31-pair) : pair;
    int split = (T+1)>>1;
    int st0 = kp ? split : 0;
    int st1 = kp ? (T+1) : split;
    int r0 = T*64 + w*16;
    s16x8 aq[2];
#pragma unroll
    for(int ks=0;ks<2;ks++) aq[ks] = *(const s16x8*)(Qb + (long)(r0+fr)*64 + ks*32 + fg*8);
    const unsigned* bmrow = bm + (long)(r0+fr)*64;
    float mrow = -1e30f, lrow = 0.f;
    f32x4 accO[4];
#pragma unroll
    for(int nf=0;nf<4;nf++){ f32x4 z = {0.f,0.f,0.f,0.f}; accO[nf]=z; }

    for(int st=st0; st<st1; st++){
      unsigned w0 = bmrow[st*2], w1 = bmrow[st*2+1];
      f32x4 sacc[4];
#pragma unroll
      for(int nf=0;nf<4;nf++){ f32x4 z = {0.f,0.f,0.f,0.f}; sacc[nf]=z; }
      // swapped QK^T: lane holds q=fr, k = nf*16 + fg*4 + r
#pragma unroll
      for(int ks=0;ks<2;ks++)
#pragma unroll
        for(int nf=0;nf<4;nf++){
          s16x8 bk = *(const s16x8*)(Kb + (long)(st*64 + nf*16 + fr)*64 + ks*32 + fg*8);
          sacc[nf] = MFMA_BF16(bk, aq[ks], sacc[nf]);
        }
      // prefetch V (ks=0 half) while softmax runs
      s16x8 bv0[4];
#pragma unroll
      for(int nf=0;nf<4;nf++) bv0[nf] = *(const s16x8*)(Vb + (long)(nf*16+fr)*2048 + st*64 + fg*8);
      // mask + row max (in-place into sacc)
      float vmax = -1e30f;
#pragma unroll
      for(int nf=0;nf<4;nf++)
#pragma unroll
        for(int r=0;r<4;r++){
          int sl = nf*16 + fg*4 + r;
          unsigned word = (sl<32) ? w0 : w1;
          bool sel = (word>>(sl&31))&1u;
          float v = sel ? sacc[nf][r] : -1e30f;
          sacc[nf][r] = v;
          vmax = fmaxf(vmax, v);
        }
      vmax = fmaxf(vmax, __shfl_xor(vmax,16));
      vmax = fmaxf(vmax, __shfl_xor(vmax,32));
      bool up = vmax > mrow;
      float mnew = fmaxf(mrow, vmax);
      float psum = 0.f;
#pragma unroll
      for(int nf=0;nf<4;nf++)
#pragma unroll
        for(int r=0;r<4;r++){
          float v = sacc[nf][r];
          float e = (v > -1e29f) ? exp2f(v - mnew) : 0.f;
          sacc[nf][r] = e; psum += e;
        }
      psum += __shfl_xor(psum,16);
      psum += __shfl_xor(psum,32);
      // pack P to per-wave LDS (no barrier: same-wave DS ordering)
#pragma unroll
      for(int nf=0;nf<4;nf++){
        *(unsigned*)&P[w][fr][nf*16 + fg*4 + 0] = cvt_pk_bf16(sacc[nf][0], sacc[nf][1]);
        *(unsigned*)&P[w][fr][nf*16 + fg*4 + 2] = cvt_pk_bf16(sacc[nf][2], sacc[nf][3]);
      }
      if(__any(up)){
        float sc = exp2f(mrow - mnew);
        lrow = lrow*sc + psum; mrow = mnew;
        float scv[4];
#pragma unroll
        for(int r=0;r<4;r++) scv[r] = __shfl(sc, fg*4 + r);
#pragma unroll
        for(int nf=0;nf<4;nf++)
#pragma unroll
          for(int r=0;r<4;r++) accO[nf][r] *= scv[r];
      } else {
        lrow += psum;
      }
#pragma unroll
      for(int ks=0;ks<2;ks++){
        s16x8 pa = *(const s16x8*)&P[w][fr][ks*32 + fg*8];
#pragma unroll
        for(int nf=0;nf<4;nf++){
          s16x8 bv = ks ? *(const s16x8*)(Vb + (long)(nf*16+fr)*2048 + st*64 + 32 + fg*8) : bv0[nf];
          accO[nf] = MFMA_BF16(pa, bv, accO[nf]);
        }
      }
    }
    // store partials: O rows q=fg*4+r, cols d=nf*16+fr ; m/l per q=fr (same across fg)
    if(fg==0) pML[pbase + r0 + fr] = make_float2(mrow, lrow);
#pragma unroll
    for(int r=0;r<4;r++){
      int trow = r0 + fg*4 + r;
#pragma unroll
      for(int nf=0;nf<4;nf++)
        pO[(pbase + trow)*64 + nf*16 + fr] = f2bf(accO[nf][r]);
    }
  }
}

// ---------- combine split-KV partials -> attn bf16 [B,S,H*64] ----------
__global__ __launch_bounds__(256) void k_attn_combine(const unsigned short* __restrict__ pO,
                                                      const float2* __restrict__ pML,
                                                      unsigned short* __restrict__ attnb){
  int gid = blockIdx.x*256 + threadIdx.x;     // 65536 rows * 8 dgroups
  int rg = gid>>3, dg = gid&7;
  long bh = rg>>11; int row = rg&2047;
  long base0 = (bh*2+0)*2048 + row;
  long base1 = (bh*2+1)*2048 + row;
  float2 ml0 = pML[base0], ml1 = pML[base1];
  float m = fmaxf(ml0.x, ml1.x);
  float w0 = exp2f(ml0.x - m), w1 = exp2f(ml1.x - m);
  float inv = 1.0f/(ml0.y*w0 + ml1.y*w1);
  s16x8 o0 = *(const s16x8*)(pO + base0*64 + dg*8);
  s16x8 o1 = *(const s16x8*)(pO + base1*64 + dg*8);
  s16x8 o;
#pragma unroll
  for(int j=0;j<8;j++){
    float v = (bf2f((unsigned short)o0[j])*w0 + bf2f((unsigned short)o1[j])*w1)*inv;
    o[j] = (short)f2bf(v);
  }
  int b = (int)(bh>>4), h = (int)(bh&15);
  *(s16x8*)(attnb + ((long)b*2048 + row)*1024 + h*64 + dg*8) = o;
}

// ---------- launcher ----------
extern "C" void kernel_launch(void* const* d_in, const int* in_sizes, int n_in,
                              void* d_out, int out_size, void* d_ws, size_t ws_size,
                              hipStream_t stream){
  (void)in_sizes; (void)n_in; (void)out_size; (void)ws_size;
  const float* x    = (const float*)d_in[0];
  const float* Wqkv = (const float*)d_in[1];
  const float* Wo   = (const float*)d_in[2];
  const float* Wqi  = (const float*)d_in[3];
  const float* Wki  = (const float*)d_in[4];
  const float* Wwi  = (const float*)d_in[5];
  const int*   pk   = (const int*)d_in[6];

  const int B=2, S=2048, D=1024, H=16;
  const long MS = (long)B*S;  // 4096

  char* ws = (char*)d_ws;
  size_t off = 0;
  auto alloc = [&](size_t bytes)->char*{
    char* p = ws + off; off = (off + bytes + 255) & ~(size_t)255; return p;
  };
  unsigned short* x_bf   = (unsigned short*)alloc(MS*D*2);
  unsigned short* wqkvT  = (unsigned short*)alloc((size_t)3*D*D*2);
  unsigned short* woT    = (unsigned short*)alloc((size_t)D*D*2);
  unsigned short* qkv_bf = (unsigned short*)alloc(MS*3*D*2);
  unsigned short* Qr     = (unsigned short*)alloc(MS*D*2);
  unsigned short* Kr     = (unsigned short*)alloc(MS*D*2);
  unsigned short* VTb    = (unsigned short*)alloc(MS*D*2);
  unsigned short* attnb  = (unsigned short*)alloc(MS*D*2);
  float* Bcat  = (float*)alloc((size_t)1024*324*4);
  float* iqkw  = (float*)alloc(MS*324*4);
  float* ikT   = (float*)alloc(MS*64*4);
  float* cosT  = (float*)alloc((size_t)S*32*4);
  float* sinT  = (float*)alloc((size_t)S*32*4);
  unsigned* bmask = (unsigned*)alloc((size_t)B*S*64*4);
  unsigned short* pO = (unsigned short*)alloc((size_t)2*B*H*S*64*2);  // 16MB
  float2* pML = (float2*)alloc((size_t)2*B*H*S*8);                    // 1MB

  // value-path inputs to bf16
  k_f32_to_bf16<<<4096,256,0,stream>>>(x, x_bf, (int)(MS*D));
  k_transpose<unsigned short><<<dim3(3*D/32, D/32, 1), dim3(32,8), 0, stream>>>(Wqkv, wqkvT, D, 3*D, 3*D, 0, 0);
  k_transpose<unsigned short><<<dim3(D/32, D/32, 1), dim3(32,8), 0, stream>>>(Wo, woT, D, D, D, 0, 0);

  // indexer path (f32): fused projection [4096][324]
  k_pack_b<<<(1024*324+255)/256,256,0,stream>>>(Wqi, Wki, Wwi, Bcat);
  k_gemm_f32<<<dim3(64,6),256,0,stream>>>(x, Bcat, iqkw, (int)MS, 324, D);
  k_transpose<float><<<dim3(2, 64, B), dim3(32,8), 0, stream>>>(iqkw + 256, ikT, S, 64, 324, (long)S*324, (long)S*64);
  k_topk2<<<dim3(S/2,B),256,0,stream>>>(iqkw, ikT, pk, bmask);

  // QKV + RoPE
  k_rope_tab<<<S*32/256,256,0,stream>>>(cosT, sinT);
  k_gemm_bf16<unsigned short><<<dim3(MS/128, 3*D/128), 256, 0, stream>>>(x_bf, wqkvT, qkv_bf, (int)MS, 3*D, D);
  k_rope_permute<<<dim3(S/64, H, B), 256, 0, stream>>>(qkv_bf, cosT, sinT, Qr, Kr, VTb);

  // masked attention (split-KV x2) + combine + output projection
  k_attn_part<<<dim3(32, H, B), 256, 0, stream>>>(Qr, Kr, VTb, bmask, pO, pML);
  k_attn_combine<<<(int)(MS*16*8/256), 256, 0, stream>>>(pO, pML, attnb);
  k_gemm_bf16<float><<<dim3(MS/128, D/128), 256, 0, stream>>>(attnb, woT, (float*)d_out, (int)MS, D, D);
}

// Round 4
// 417.534 us; speedup vs baseline: 1.9905x; 1.1772x over previous
//
#include <hip/hip_runtime.h>
#include <stdint.h>

// ---------- types & helpers ----------
typedef short s16x8 __attribute__((ext_vector_type(8)));
typedef float f32x4 __attribute__((ext_vector_type(4)));

#define MFMA_BF16(a,b,c) __builtin_amdgcn_mfma_f32_16x16x32_bf16((a),(b),(c),0,0,0)

static __device__ __forceinline__ float bf2f(unsigned short b){
  return __uint_as_float(((unsigned)b)<<16);
}
static __device__ __forceinline__ unsigned short f2bf(float f){
  unsigned u = __float_as_uint(f);
  unsigned r = u + 0x7FFFu + ((u>>16)&1u);
  return (unsigned short)(r>>16);
}
static __device__ __forceinline__ unsigned cvt_pk_bf16(float lo, float hi){
  unsigned r; asm("v_cvt_pk_bf16_f32 %0, %1, %2" : "=v"(r) : "v"(lo), "v"(hi)); return r;
}
static __device__ __forceinline__ void store_val(float* p, float v){ *p = v; }
static __device__ __forceinline__ void store_val(unsigned short* p, float v){ *p = f2bf(v); }

// order-preserving float->u32 (descending float == descending u32), +-0 canonicalized
static __device__ __forceinline__ unsigned ordf(float f){
  if (f == 0.0f) return 0x80000000u;
  unsigned u = __float_as_uint(f);
  return (u & 0x80000000u) ? ~u : (u | 0x80000000u);
}

typedef __attribute__((address_space(1))) const void g_void;
typedef __attribute__((address_space(3))) void l_void;
static __device__ __forceinline__ void gload_lds16(const void* g, void* lds){
  __builtin_amdgcn_global_load_lds((g_void*)g, (l_void*)lds, 16, 0, 0);
}

// ---------- elementwise convert f32 -> bf16 ----------
__global__ __launch_bounds__(256) void k_f32_to_bf16(const float* __restrict__ in,
                                                     unsigned short* __restrict__ out, int n){
  int i = blockIdx.x*256 + threadIdx.x;
  int stride = gridDim.x*256;
  for(; i<n; i+=stride) out[i] = f2bf(in[i]);
}

// ---------- pack Wqi|Wki|Wwi into Bcat [1024][324] ----------
__global__ __launch_bounds__(256) void k_pack_b(const float* __restrict__ Wqi, const float* __restrict__ Wki,
                                                const float* __restrict__ Wwi, float* __restrict__ Bcat){
  int i = blockIdx.x*256 + threadIdx.x;
  if(i >= 1024*324) return;
  int kk = i/324, j = i - kk*324;
  float v = (j<256) ? Wqi[kk*256+j] : (j<320) ? Wki[kk*64 + (j-256)] : Wwi[kk*4 + (j-320)];
  Bcat[i] = v;
}

// ---------- transpose: in[R][C] (row stride inRS) f32 -> out[C][R] ----------
template<typename OT>
__global__ __launch_bounds__(256) void k_transpose(const float* __restrict__ in, OT* __restrict__ out,
                                                   int R, int C, int inRS, long zIn, long zOut){
  __shared__ float tile[32][33];
  const float* inb = in + (long)blockIdx.z*zIn;
  OT* outb = out + (long)blockIdx.z*zOut;
  int tx = threadIdx.x, ty = threadIdx.y;        // block (32,8)
  int c0 = blockIdx.x*32, r0 = blockIdx.y*32;
#pragma unroll
  for(int j=0;j<4;j++) tile[ty+j*8][tx] = inb[(long)(r0+ty+j*8)*inRS + c0 + tx];
  __syncthreads();
#pragma unroll
  for(int j=0;j<4;j++) store_val(&outb[(long)(c0+ty+j*8)*R + r0 + tx], tile[tx][ty+j*8]);
}

// ---------- generic f32 GEMM ----------
__global__ __launch_bounds__(256) void k_gemm_f32(const float* __restrict__ A, const float* __restrict__ B,
                                                  float* __restrict__ C, int M, int N, int K){
  __shared__ float As[64][17];
  __shared__ float Bs[16][68];
  int tid = threadIdx.x;
  int tx = tid & 15, ty = tid >> 4;
  int m0 = blockIdx.x*64, n0 = blockIdx.y*64;
  float acc[4][4] = {};
  for(int k0=0; k0<K; k0+=16){
#pragma unroll
    for(int i=0;i<4;i++){
      int e = tid + i*256; int rr = e>>4, cc = e&15;
      As[rr][cc] = A[(long)(m0+rr)*K + k0 + cc];
    }
#pragma unroll
    for(int i=0;i<4;i++){
      int e = tid + i*256; int rr = e>>6, cc = e&63;
      int n = n0 + cc;
      Bs[rr][cc] = (n<N) ? B[(long)(k0+rr)*N + n] : 0.f;
    }
    __syncthreads();
#pragma unroll
    for(int kk=0;kk<16;kk++){
      float av[4], bv[4];
#pragma unroll
      for(int i=0;i<4;i++) av[i] = As[ty*4+i][kk];
#pragma unroll
      for(int j=0;j<4;j++) bv[j] = Bs[kk][tx*4+j];
#pragma unroll
      for(int i=0;i<4;i++)
#pragma unroll
        for(int j=0;j<4;j++) acc[i][j] = fmaf(av[i], bv[j], acc[i][j]);
    }
    __syncthreads();
  }
#pragma unroll
  for(int i=0;i<4;i++){
    int m = m0 + ty*4 + i;
#pragma unroll
    for(int j=0;j<4;j++){
      int n = n0 + tx*4 + j;
      if(n<N) C[(long)m*N + n] = acc[i][j];
    }
  }
}

// ---------- bf16 MFMA GEMM: C[M][N] = A[M][K] * BT[N][K]^T ----------
template<typename OT>
__global__ __launch_bounds__(256) void k_gemm_bf16(const unsigned short* __restrict__ A,
                                                   const unsigned short* __restrict__ BT,
                                                   OT* __restrict__ C, int M, int N, int K){
  __shared__ __align__(16) unsigned short As[128*32];
  __shared__ __align__(16) unsigned short Bs[128*32];
  int tid = threadIdx.x;
  int w = tid>>6, l = tid&63;
  int fr = l&15, fg = l>>4;
  int wm = (w>>1)*64, wn = (w&1)*64;
  long m0 = (long)blockIdx.x*128, n0 = (long)blockIdx.y*128;
  f32x4 acc[4][4];
#pragma unroll
  for(int i=0;i<4;i++)
#pragma unroll
    for(int j=0;j<4;j++){ f32x4 z = {0.f,0.f,0.f,0.f}; acc[i][j]=z; }

  for(int k0=0;k0<K;k0+=32){
    __syncthreads();
#pragma unroll
    for(int i=0;i<2;i++){
      int eo = (w*64 + l)*8 + i*2048;
      int rr = eo>>5, cc = eo&31;
      gload_lds16(A + (m0+rr)*K + k0 + cc, (char*)As + w*1024 + i*4096);
    }
#pragma unroll
    for(int i=0;i<2;i++){
      int eo = (w*64 + l)*8 + i*2048;
      int rr = eo>>5, cc = eo&31;
      gload_lds16(BT + (n0+rr)*K + k0 + cc, (char*)Bs + w*1024 + i*4096);
    }
    asm volatile("s_waitcnt vmcnt(0)" ::: "memory");
    __syncthreads();
    s16x8 af[4], bfr[4];
#pragma unroll
    for(int mf=0;mf<4;mf++) af[mf]  = *(const s16x8*)&As[(wm + mf*16 + fr)*32 + fg*8];
#pragma unroll
    for(int nf=0;nf<4;nf++) bfr[nf] = *(const s16x8*)&Bs[(wn + nf*16 + fr)*32 + fg*8];
#pragma unroll
    for(int mf=0;mf<4;mf++)
#pragma unroll
      for(int nf=0;nf<4;nf++)
        acc[mf][nf] = MFMA_BF16(af[mf], bfr[nf], acc[mf][nf]);
  }
#pragma unroll
  for(int mf=0;mf<4;mf++)
#pragma unroll
    for(int nf=0;nf<4;nf++)
#pragma unroll
      for(int r=0;r<4;r++){
        long m = m0 + wm + mf*16 + fg*4 + r;
        long n = n0 + wn + nf*16 + fr;
        store_val(&C[m*N + n], acc[mf][nf][r]);
      }
}

// ---------- RoPE tables ----------
__global__ __launch_bounds__(256) void k_rope_tab(float* __restrict__ cosT, float* __restrict__ sinT){
  int i = blockIdx.x*256 + threadIdx.x;   // 2048*32
  int t = i>>5, p = i&31;
  float theta = exp2f(-(float)p * (13.287712379549449f/32.0f)); // 10000^(-p/32)
  float ang = (float)t * theta;
  cosT[i] = cosf(ang);
  sinT[i] = sinf(ang);
}

// ---------- RoPE + head-permute; Q prescaled by 0.125*log2(e) (exp2 domain) ----------
__global__ __launch_bounds__(256) void k_rope_permute(const unsigned short* __restrict__ qkv,
                                                      const float* __restrict__ cosT, const float* __restrict__ sinT,
                                                      unsigned short* __restrict__ Qr, unsigned short* __restrict__ Kr,
                                                      unsigned short* __restrict__ VT){
  int st = blockIdx.x, h = blockIdx.y, b = blockIdx.z;
  int tid = threadIdx.x;
  __shared__ float vt[64][65];
  long rowbase = (long)b*2048 + st*64;
#pragma unroll
  for(int part=0; part<2; part++){
    const int colbase = part*1024 + h*64;
    unsigned short* outp = part ? Kr : Qr;
    float prescale = part ? 1.0f : 0.18033688011112042f;   // 0.125 * log2(e)
#pragma unroll
    for(int i=0;i<8;i++){
      int e = tid + i*256;            // 64 rows x 32 pairs
      int row = e>>5, p = e&31;
      long s = (long)st*64 + row;
      const unsigned short* src = qkv + (rowbase+row)*3072 + colbase + 2*p;
      float x0 = bf2f(src[0]), x1 = bf2f(src[1]);
      float c = cosT[s*32+p], sn = sinT[s*32+p];
      float y0 = (x0*c - x1*sn)*prescale;
      float y1 = (x1*c + x0*sn)*prescale;
      unsigned short* dst = outp + ((long)(b*16+h)*2048 + s)*64 + 2*p;
      dst[0] = f2bf(y0); dst[1] = f2bf(y1);
    }
  }
#pragma unroll
  for(int i=0;i<16;i++){
    int e = tid + i*256;
    int row = e>>6, col = e&63;
    vt[col][row] = bf2f(qkv[(rowbase+row)*3072 + 2048 + h*64 + col]);
  }
  __syncthreads();
#pragma unroll
  for(int i=0;i<16;i++){
    int e = tid + i*256;
    int d = e>>6, scol = e&63;
    VT[((long)(b*16+h)*64 + d)*2048 + (long)st*64 + scol] = f2bf(vt[d][scol]);
  }
}

// ---------- per-row index scores + exact top-k (stable ties) -> bitmask ----------
__global__ __launch_bounds__(256) void k_topk2(const float* __restrict__ iqkw, const float* __restrict__ ikT,
                                               const int* __restrict__ pk, unsigned* __restrict__ bmask){
  int b = blockIdx.y;
  int tid = threadIdx.x;
  int w = tid>>6, lane = tid&63;
  int k = pk[0];
  __shared__ float siq[256];
  __shared__ float siw[4];
  __shared__ unsigned su[2048];
  __shared__ unsigned hist4[4][256];
  __shared__ unsigned chunk[4];
  __shared__ unsigned words[64];
  __shared__ unsigned sh_b[2];
  const int s0 = tid*8;

  for(int rp=0; rp<2; rp++){
    int t = rp ? (2047 - (int)blockIdx.x) : (int)blockIdx.x;
    long row = (long)b*2048 + t;
    siq[tid] = iqkw[row*324 + tid];
    if(tid<4) siw[tid] = iqkw[row*324 + 320 + tid];
    __syncthreads();

    // ---- scores for s in [s0, s0+8) ----
    if (s0 <= t){
      float acc[4][8];
#pragma unroll
      for(int h=0;h<4;h++)
#pragma unroll
        for(int j=0;j<8;j++) acc[h][j]=0.f;
      const float* ikb = ikT + (long)b*64*2048;
      for(int d=0;d<64;d++){
        const float* prow = ikb + (long)d*2048 + s0;
        float4 v0 = *(const float4*)prow;
        float4 v1 = *(const float4*)(prow+4);
        float ikv[8] = {v0.x,v0.y,v0.z,v0.w,v1.x,v1.y,v1.z,v1.w};
#pragma unroll
        for(int h=0;h<4;h++){
          float q = siq[h*64+d];
#pragma unroll
          for(int j=0;j<8;j++) acc[h][j] = fmaf(q, ikv[j], acc[h][j]);
        }
      }
#pragma unroll
      for(int j=0;j<8;j++){
        int s = s0+j;
        if(s<=t){
          float I = 0.f;
#pragma unroll
          for(int h=0;h<4;h++) I += siw[h]*fmaxf(acc[h][j],0.f);
          su[s] = ordf(I);
        }
      }
    }
    __syncthreads();

    // ---- exact top-k threshold via 4x 8-bit radix, wave-level scans ----
    unsigned thr = 0; int kk = 0;
    bool allsel = (t+1 <= k);
    if (!allsel){
      unsigned prefix=0, msk=0;
      kk = k;
      for(int shift=24; shift>=0; shift-=8){
#pragma unroll
        for(int i=0;i<4;i++) hist4[i][tid]=0;
        __syncthreads();
        if(s0<=t){
          for(int j=0;j<8;j++){
            int s=s0+j; if(s>t) break;
            unsigned u=su[s];
            if((u&msk)==prefix) atomicAdd(&hist4[w][(u>>shift)&255],1u);
          }
        }
        __syncthreads();
        unsigned hv = hist4[0][tid]+hist4[1][tid]+hist4[2][tid]+hist4[3][tid];
        unsigned sfx = hv;
#pragma unroll
        for(int off=1; off<64; off<<=1){
          unsigned tmp = __shfl_down(sfx, off);
          if(lane < 64-off) sfx += tmp;
        }
        if(lane==0) chunk[w] = sfx;
        __syncthreads();
        unsigned above = 0;
#pragma unroll
        for(int c=0;c<4;c++) if(c>w) above += chunk[c];
        unsigned incl = sfx + above;
        unsigned cb   = incl - hv;
        if(cb < (unsigned)kk && incl >= (unsigned)kk){ sh_b[0]=(unsigned)tid; sh_b[1]=(unsigned)kk-cb; }
        __syncthreads();
        prefix |= sh_b[0]<<shift; msk |= 255u<<shift; kk = (int)sh_b[1];
        __syncthreads();
      }
      thr = prefix;
    }

    // ---- emit bits ----
    unsigned gtb=0, eqb=0;
    if (s0 <= t){
      for(int j=0;j<8;j++){
        int s=s0+j; if(s>t) break;
        if(allsel){ gtb |= 1u<<j; }
        else{
          unsigned u=su[s];
          if(u>thr) gtb |= 1u<<j;
          else if(u==thr) eqb |= 1u<<j;
        }
      }
    }
    int cnt = __popc(eqb);
    unsigned pfx = (unsigned)cnt;
#pragma unroll
    for(int off=1; off<64; off<<=1){
      unsigned tmp = __shfl_up(pfx, off);
      if(lane >= off) pfx += tmp;
    }
    if(lane==63) chunk[w] = pfx;
    __syncthreads();
    unsigned below = 0;
#pragma unroll
    for(int c=0;c<4;c++) if(c<w) below += chunk[c];
    int excl = (int)(pfx - (unsigned)cnt + below);
    unsigned bits = gtb;
    if(eqb){
      int seen=0;
      for(int j=0;j<8;j++) if((eqb>>j)&1u){ if(excl+seen < kk) bits |= 1u<<j; seen++; }
    }
    if(tid<64) words[tid]=0;
    __syncthreads();
    if(bits) atomicOr(&words[tid>>2], bits << ((tid&3)*8));
    __syncthreads();
    if(tid<64) bmask[row*64 + tid] = words[tid];
    __syncthreads();
  }
}

// ---------- staging: K/V 64x64 bf16 tile -> LDS, XOR-swizzled via pre-swizzled global source ----------
// LDS layout: element (row, d) at index row*64 + (d ^ ((row&7)<<3))  [bytes: row*128 + (2d ^ ((row&7)<<4))]
static __device__ __forceinline__ void stage_kv(const unsigned short* __restrict__ Kb,
                                                const unsigned short* __restrict__ Vb,
                                                unsigned short* Ksb, unsigned short* Vsb,
                                                int st, int w, int l){
#pragma unroll
  for(int i=0;i<2;i++){
    int s = i*256 + w*64 + l;          // 16B slot id, 512 slots per tile
    int row = s>>3, c16 = s&7;
    int col = (c16 ^ (row&7))*8;       // element offset of this slot's source
    gload_lds16(Kb + (long)(st*64 + row)*64 + col, (char*)Ksb + (i*256 + w*64)*16);
    gload_lds16(Vb + (long)row*2048 + st*64 + col, (char*)Vsb + (i*256 + w*64)*16);
  }
}

// ---------- masked flash attention: LDS-staged K/V, swapped-QK, XCD-swizzled ----------
// 512 blocks; block handles ttiles {xb, 31-xb} for one (b,h); 4 (b,h) pairs per XCD.
__global__ __launch_bounds__(256) void k_attn(const unsigned short* __restrict__ Qr,
                                              const unsigned short* __restrict__ Kr,
                                              const unsigned short* __restrict__ VT,
                                              const unsigned* __restrict__ bmask,
                                              unsigned short* __restrict__ attn){
  // XCD-aware remap: fid%8 = XCD (dispatch heuristic); give each XCD 4 whole (b,h) pairs
  int fid = blockIdx.x + (blockIdx.y<<4) + (blockIdx.z<<8);   // 0..511
  int xcd = fid & 7, slot = fid >> 3;
  int bh  = (xcd<<2) + (slot>>4);      // 0..31
  int xb  = slot & 15;
  int b = bh>>4, h = bh&15;

  int tid = threadIdx.x, w = tid>>6, l = tid&63;
  int fr = l&15, fg = l>>4;
  __shared__ __align__(16) unsigned short Ks[2][64*64];
  __shared__ __align__(16) unsigned short Vs[2][64*64];
  __shared__ __align__(16) unsigned short P[4][16][72];   // per-wave private slice
  const unsigned short* Qb = Qr + (long)bh*2048*64;
  const unsigned short* Kb = Kr + (long)bh*2048*64;
  const unsigned short* Vb = VT + (long)bh*64*2048;
  const unsigned* bm = bmask + (long)b*2048*64;
  const int swz = (fr&7)<<3;           // element-index XOR for this lane's frag reads

#pragma unroll 1
  for(int pass=0; pass<2; pass++){
    int T = pass ? (31-xb) : xb;
    int r0 = T*64 + w*16;
    s16x8 aq[2];
#pragma unroll
    for(int ks=0;ks<2;ks++) aq[ks] = *(const s16x8*)(Qb + (long)(r0+fr)*64 + ks*32 + fg*8);
    const unsigned* bmrow = bm + (long)(r0+fr)*64;
    float mrow = -1e30f, lrow = 0.f;
    f32x4 accO[4];
#pragma unroll
    for(int nf=0;nf<4;nf++){ f32x4 z = {0.f,0.f,0.f,0.f}; accO[nf]=z; }

    // prologue: stage tile 0
    stage_kv(Kb, Vb, Ks[0], Vs[0], 0, w, l);
    asm volatile("s_waitcnt vmcnt(0)" ::: "memory");
    __syncthreads();
    int cur = 0;

#pragma unroll 1
    for(int st=0; st<=T; st++){
      if(st < T) stage_kv(Kb, Vb, Ks[cur^1], Vs[cur^1], st+1, w, l);
      unsigned w0 = bmrow[st*2], w1 = bmrow[st*2+1];
      // QK^T (swapped): lane holds q=fr, k = nf*16 + fg*4 + r
      f32x4 sacc[4];
#pragma unroll
      for(int nf=0;nf<4;nf++){ f32x4 z = {0.f,0.f,0.f,0.f}; sacc[nf]=z; }
#pragma unroll
      for(int ks=0;ks<2;ks++)
#pragma unroll
        for(int nf=0;nf<4;nf++){
          s16x8 bk = *(const s16x8*)&Ks[cur][(nf*16+fr)*64 + ((ks*32+fg*8) ^ swz)];
          sacc[nf] = MFMA_BF16(bk, aq[ks], sacc[nf]);
        }
      // V frags (independent of softmax; compiler may hoist)
      s16x8 bvf[2][4];
#pragma unroll
      for(int ks=0;ks<2;ks++)
#pragma unroll
        for(int nf=0;nf<4;nf++)
          bvf[ks][nf] = *(const s16x8*)&Vs[cur][(nf*16+fr)*64 + ((ks*32+fg*8) ^ swz)];
      // mask + online softmax (exp2 domain)
      float vmax = -1e30f;
#pragma unroll
      for(int nf=0;nf<4;nf++){
        unsigned bits4 = ((nf<2) ? w0 : w1) >> ((nf&1)*16 + fg*4);
#pragma unroll
        for(int r=0;r<4;r++){
          float v = ((bits4>>r)&1u) ? sacc[nf][r] : -1e30f;
          sacc[nf][r] = v;
          vmax = fmaxf(vmax, v);
        }
      }
      vmax = fmaxf(vmax, __shfl_xor(vmax,16));
      vmax = fmaxf(vmax, __shfl_xor(vmax,32));
      bool up = vmax > mrow;
      float mnew = fmaxf(mrow, vmax);
      float psum = 0.f;
#pragma unroll
      for(int nf=0;nf<4;nf++)
#pragma unroll
        for(int r=0;r<4;r++){
          float v = sacc[nf][r];
          float e = (v > -1e29f) ? exp2f(v - mnew) : 0.f;
          sacc[nf][r] = e; psum += e;
        }
      psum += __shfl_xor(psum,16);
      psum += __shfl_xor(psum,32);
      // pack P to per-wave LDS (same-wave DS ordering; no barrier)
#pragma unroll
      for(int nf=0;nf<4;nf++){
        *(unsigned*)&P[w][fr][nf*16 + fg*4 + 0] = cvt_pk_bf16(sacc[nf][0], sacc[nf][1]);
        *(unsigned*)&P[w][fr][nf*16 + fg*4 + 2] = cvt_pk_bf16(sacc[nf][2], sacc[nf][3]);
      }
      if(__any(up)){
        float sc = exp2f(mrow - mnew);
        lrow = lrow*sc + psum; mrow = mnew;
        float scv[4];
#pragma unroll
        for(int r=0;r<4;r++) scv[r] = __shfl(sc, fg*4 + r);
#pragma unroll
        for(int nf=0;nf<4;nf++)
#pragma unroll
          for(int r=0;r<4;r++) accO[nf][r] *= scv[r];
      } else {
        lrow += psum;
      }
#pragma unroll
      for(int ks=0;ks<2;ks++){
        s16x8 pa = *(const s16x8*)&P[w][fr][ks*32 + fg*8];
#pragma unroll
        for(int nf=0;nf<4;nf++)
          accO[nf] = MFMA_BF16(pa, bvf[ks][nf], accO[nf]);
      }
      asm volatile("s_waitcnt vmcnt(0)" ::: "memory");
      __syncthreads();
      cur ^= 1;
    }
    float linv[4];
#pragma unroll
    for(int r=0;r<4;r++) linv[r] = 1.0f/__shfl(lrow, fg*4 + r);
#pragma unroll
    for(int r=0;r<4;r++){
      int trow = r0 + fg*4 + r;
#pragma unroll
      for(int nf=0;nf<4;nf++)
        attn[((long)b*2048 + trow)*1024 + h*64 + nf*16 + fr] = f2bf(accO[nf][r]*linv[r]);
    }
  }
}

// ---------- launcher ----------
extern "C" void kernel_launch(void* const* d_in, const int* in_sizes, int n_in,
                              void* d_out, int out_size, void* d_ws, size_t ws_size,
                              hipStream_t stream){
  (void)in_sizes; (void)n_in; (void)out_size; (void)ws_size;
  const float* x    = (const float*)d_in[0];
  const float* Wqkv = (const float*)d_in[1];
  const float* Wo   = (const float*)d_in[2];
  const float* Wqi  = (const float*)d_in[3];
  const float* Wki  = (const float*)d_in[4];
  const float* Wwi  = (const float*)d_in[5];
  const int*   pk   = (const int*)d_in[6];

  const int B=2, S=2048, D=1024, H=16;
  const long MS = (long)B*S;  // 4096

  char* ws = (char*)d_ws;
  size_t off = 0;
  auto alloc = [&](size_t bytes)->char*{
    char* p = ws + off; off = (off + bytes + 255) & ~(size_t)255; return p;
  };
  unsigned short* x_bf   = (unsigned short*)alloc(MS*D*2);
  unsigned short* wqkvT  = (unsigned short*)alloc((size_t)3*D*D*2);
  unsigned short* woT    = (unsigned short*)alloc((size_t)D*D*2);
  unsigned short* qkv_bf = (unsigned short*)alloc(MS*3*D*2);
  unsigned short* Qr     = (unsigned short*)alloc(MS*D*2);
  unsigned short* Kr     = (unsigned short*)alloc(MS*D*2);
  unsigned short* VTb    = (unsigned short*)alloc(MS*D*2);
  unsigned short* attnb  = (unsigned short*)alloc(MS*D*2);
  float* Bcat  = (float*)alloc((size_t)1024*324*4);
  float* iqkw  = (float*)alloc(MS*324*4);
  float* ikT   = (float*)alloc(MS*64*4);
  float* cosT  = (float*)alloc((size_t)S*32*4);
  float* sinT  = (float*)alloc((size_t)S*32*4);
  unsigned* bmask = (unsigned*)alloc((size_t)B*S*64*4);

  // value-path inputs to bf16
  k_f32_to_bf16<<<4096,256,0,stream>>>(x, x_bf, (int)(MS*D));
  k_transpose<unsigned short><<<dim3(3*D/32, D/32, 1), dim3(32,8), 0, stream>>>(Wqkv, wqkvT, D, 3*D, 3*D, 0, 0);
  k_transpose<unsigned short><<<dim3(D/32, D/32, 1), dim3(32,8), 0, stream>>>(Wo, woT, D, D, D, 0, 0);

  // indexer path (f32): fused projection [4096][324]
  k_pack_b<<<(1024*324+255)/256,256,0,stream>>>(Wqi, Wki, Wwi, Bcat);
  k_gemm_f32<<<dim3(64,6),256,0,stream>>>(x, Bcat, iqkw, (int)MS, 324, D);
  k_transpose<float><<<dim3(2, 64, B), dim3(32,8), 0, stream>>>(iqkw + 256, ikT, S, 64, 324, (long)S*324, (long)S*64);
  k_topk2<<<dim3(S/2,B),256,0,stream>>>(iqkw, ikT, pk, bmask);

  // QKV + RoPE
  k_rope_tab<<<S*32/256,256,0,stream>>>(cosT, sinT);
  k_gemm_bf16<unsigned short><<<dim3(MS/128, 3*D/128), 256, 0, stream>>>(x_bf, wqkvT, qkv_bf, (int)MS, 3*D, D);
  k_rope_permute<<<dim3(S/64, H, B), 256, 0, stream>>>(qkv_bf, cosT, sinT, Qr, Kr, VTb);

  // masked attention + output projection
  k_attn<<<dim3(16, H, B), 256, 0, stream>>>(Qr, Kr, VTb, bmask, attnb);
  k_gemm_bf16<float><<<dim3(MS/128, D/128), 256, 0, stream>>>(attnb, woT, (float*)d_out, (int)MS, D, D);
}